// Round 9
// baseline (11015.299 us; speedup 1.0000x reference)
//
#include <hip/hip_runtime.h>
#include <hip/hip_bf16.h>
#include <math.h>

#define NN 50000
#define NE 400000
#define HD 128
#define NB 64
#define CN 3125          // nodes per chunk
#define NCH 16           // chunks (CN*NCH == NN)
#define EC_MAX 28672     // max edges per chunk (mean 25000, sigma~153, 24-sigma margin)

typedef __hip_bfloat16 bf16;

__device__ __forceinline__ float sigm_(float x){ return 1.f/(1.f+__expf(-x)); }
__device__ __forceinline__ float silu_(float x){ return x*sigm_(x); }
__device__ __forceinline__ float bf2f(bf16 x){ return __bfloat162float(x); }
__device__ __forceinline__ bool finite_(float v){ return fabsf(v) <= 1e37f; }
// flagged load/store: bf==1 -> bf16 storage, else fp32
__device__ __forceinline__ float ldx(const void* p, size_t i, int bf){
    return bf ? bf2f(((const bf16*)p)[i]) : ((const float*)p)[i];
}
__device__ __forceinline__ void stx(void* p, size_t i, int bf, float v){
    if (bf) ((bf16*)p)[i] = __float2bfloat16(v); else ((float*)p)[i] = v;
}

enum { M_PLAIN=0, M_BIAS, M_SILU, M_BNSILU, M_MSG };

// ---------------- generic tiled GEMM: C[M,128] = epilogue(A[M,K] @ W[K,128]) ----------
template<int MODE, int GA>
__global__ __launch_bounds__(256)
void gemmk(const void* __restrict__ Av, int akf,
           const float* __restrict__ W, const float* __restrict__ bias,
           const float* __restrict__ gg, const float* __restrict__ be,
           const int* __restrict__ elist, int n0cn,
           const int* __restrict__ srcI, const int* __restrict__ dstI,
           const void* __restrict__ AnB, int anf, const float* __restrict__ Bnc,
           const int* __restrict__ rp, int rn0, int rn1,
           void* __restrict__ Cv, int owf, int M, int K)
{
    int Ml = M, cbase = 0;
    if (rp){
        int e0 = rp[rn0], e1 = rp[rn1];
        cbase = e0;
        int ec = e1 - e0;
        Ml = min(M, max(ec, 0));
    }
    const int row0 = blockIdx.x * 64;
    if (row0 >= Ml) return;

    __shared__ float As[32][68];
    __shared__ float Ws[32][128];
    const int tid = threadIdx.x;
    const int tx = tid & 15, ty = tid >> 4;
    float acc[4][8];
#pragma unroll
    for (int r=0;r<4;++r)
#pragma unroll
        for (int j=0;j<8;++j) acc[r][j]=0.f;

    const int mload = tid >> 2;
    const int kload = (tid & 3) << 3;

    int grow = row0 + mload;
    bool rowValid = grow < Ml;
    int arow = grow;
    if (GA && rowValid){
        int ee = elist[cbase + grow];
        arow = min(max(ee, 0), NE-1);
    }

    for (int k0 = 0; k0 < K; k0 += 32) {
#pragma unroll
        for (int j=0;j<8;++j){
            int kg = k0 + kload + j;
            As[kload+j][mload] = (rowValid && kg<K) ? ldx(Av, (size_t)arow*K+kg, akf) : 0.f;
        }
#pragma unroll
        for (int j=0;j<16;++j){
            int el = tid*16 + j;
            int kk = el >> 7, col = el & 127;
            int kg = k0 + kk;
            Ws[kk][col] = (kg < K) ? W[(size_t)kg*HD + col] : 0.f;
        }
        __syncthreads();
#pragma unroll
        for (int k=0;k<32;++k){
            float av[4], wv[8];
#pragma unroll
            for (int r=0;r<4;++r) av[r] = As[k][ty*4+r];
#pragma unroll
            for (int j=0;j<8;++j) wv[j] = Ws[k][tx*8+j];
#pragma unroll
            for (int r=0;r<4;++r)
#pragma unroll
                for (int j=0;j<8;++j) acc[r][j] += av[r]*wv[j];
        }
        __syncthreads();
    }
    const int col0 = tx*8;
#pragma unroll
    for (int r=0;r<4;++r){
        int orow = row0 + ty*4 + r;
        if (orow >= Ml) continue;
        float o[8];
#pragma unroll
        for (int j=0;j<8;++j) o[j]=acc[r][j];
        if constexpr (MODE==M_BIAS || MODE==M_SILU || MODE==M_BNSILU || MODE==M_MSG){
#pragma unroll
            for (int j=0;j<8;++j) o[j] += bias[col0+j];
        }
        if constexpr (MODE==M_BNSILU){
#pragma unroll
            for (int j=0;j<8;++j) o[j] = o[j]*gg[col0+j] + be[col0+j];
        }
        if constexpr (MODE==M_MSG){
            int ee = elist[cbase + orow];
            ee = min(max(ee,0), NE-1);
            int se = srcI[ee]; se = min(max(se,0), NN-1);
            int de = dstI[ee] - n0cn; de = min(max(de,0), CN-1);
#pragma unroll
            for (int j=0;j<8;++j)
                o[j] += ldx(AnB, (size_t)se*HD+col0+j, anf) + Bnc[(size_t)de*HD+col0+j];
        }
        if constexpr (MODE==M_SILU || MODE==M_BNSILU || MODE==M_MSG){
#pragma unroll
            for (int j=0;j<8;++j) o[j] = silu_(o[j]);
        }
#pragma unroll
        for (int j=0;j<8;++j) stx(Cv, (size_t)orow*HD + col0 + j, owf, o[j]);
    }
}

// ---------------- CSR build (int atomics only) ----------------
__global__ void hist_kernel(const int* __restrict__ idx, int* __restrict__ cnt, int n, int nb){
    int i = blockIdx.x*256 + threadIdx.x;
    if (i < n){
        int v = idx[i]; v = min(max(v,0), nb-1);
        atomicAdd(&cnt[v], 1);
    }
}

__global__ void scan_kernel(const int* __restrict__ cnt, int* __restrict__ out, int n){
    __shared__ int sums[256];
    int t = threadIdx.x;
    int chunk = (n + 255) / 256;
    int lo = t*chunk, hi = lo+chunk; if (hi > n) hi = n; if (lo > n) lo = n;
    int s = 0;
    for (int i=lo;i<hi;++i) s += cnt[i];
    sums[t] = s;
    __syncthreads();
    if (t==0){ int run=0; for (int i=0;i<256;++i){ int v=sums[i]; sums[i]=run; run+=v; } }
    __syncthreads();
    int run = sums[t];
    for (int i=lo;i<hi;++i){ out[i]=run; run+=cnt[i]; }
    if (hi == n) out[n] = run;
}

__global__ void fill_kernel(const int* __restrict__ dst, const int* __restrict__ rowptr,
                            int* __restrict__ cur, int* __restrict__ elist, int n){
    int e = blockIdx.x*256 + threadIdx.x;
    if (e < n){
        int d = dst[e]; d = min(max(d,0), NN-1);
        int slot = atomicAdd(&cur[d], 1);
        int p = rowptr[d] + slot;
        if (p >= 0 && p < NE) elist[p] = e;
    }
}

// gptr from SORTED batch, no atomics: each gptr[g] written exactly once
__global__ void gptr_kernel(const int* __restrict__ batch, int* __restrict__ gptr){
    int n = blockIdx.x*256 + threadIdx.x;
    if (n >= NN) return;
    int b = batch[n]; b = min(max(b,0), NB-1);
    if (n == 0){
        for (int g=0; g<=b; ++g) gptr[g] = 0;
    } else {
        int bp = batch[n-1]; bp = min(max(bp,0), NB-1);
        for (int g=bp+1; g<=b; ++g) gptr[g] = n;
    }
    if (n == NN-1){
        for (int g=b+1; g<=NB; ++g) gptr[g] = NN;
    }
}

__global__ void posf_kernel(const float* __restrict__ pos, float* __restrict__ posf){
    int i = blockIdx.x*256 + threadIdx.x;
    if (i < NN*3) posf[i] = pos[i];
}

// xv[n][c][h] = xw[n][h] * posf[n][c]
__global__ void xv_init(const float* __restrict__ xw, const float* __restrict__ posf,
                        void* __restrict__ xv, int xvf){
    int n = blockIdx.x, h = threadIdx.x;
    float v = xw[(size_t)n*HD+h];
    stx(xv, (size_t)n*3*HD + h,        xvf, v*posf[n*3+0]);
    stx(xv, (size_t)n*3*HD + HD + h,   xvf, v*posf[n*3+1]);
    stx(xv, (size_t)n*3*HD + 2*HD + h, xvf, v*posf[n*3+2]);
}

// fused per-node aggregation + Wv2/Wsx/Wsa GEMVs for one chunk (chunk-local outputs)
__global__ __launch_bounds__(128)
void scatter_fused(const int* __restrict__ rp, const int* __restrict__ elist,
                   const int* __restrict__ srcI, const float* __restrict__ posf,
                   const void* __restrict__ mB, const void* __restrict__ g1B, int ebf,
                   const void* __restrict__ xvO, int xvf, const float* __restrict__ xs,
                   const float* __restrict__ Wv2, const float* __restrict__ bv2,
                   const float* __restrict__ Wsx, const float* __restrict__ Wsa,
                   const float* __restrict__ bs,
                   float* __restrict__ sumvC, float* __restrict__ xscC, int n0)
{
    __shared__ float mdS[3][128];
    __shared__ float smS[128];
    __shared__ float xsS[128];
    const int b = blockIdx.x;
    const int n = n0 + b;
    const int h = threadIdx.x;
    const int cbase = rp[n0];
    int p0 = rp[n], p1 = rp[n+1];
    float px0 = posf[n*3], px1 = posf[n*3+1], px2 = posf[n*3+2];
    float sm=0, av0=0,av1=0,av2=0, md0=0,md1=0,md2=0, sd0=0,sd1=0,sd2=0;
    for (int p=p0; p<p1; ++p){
        int i = p - cbase;
        if ((unsigned)i >= (unsigned)EC_MAX) break;
        int e = elist[p]; e = min(max(e,0), NE-1);
        float mh = ldx(mB, (size_t)i*HD + h, ebf);
        float gh = ldx(g1B, (size_t)i*HD + h, ebf);
        int sn = srcI[e]; sn = min(max(sn,0), NN-1);
        float d0 = px0 - posf[sn*3+0];
        float d1 = px1 - posf[sn*3+1];
        float d2 = px2 - posf[sn*3+2];
        sm += mh;
        av0 += ldx(xvO, (size_t)sn*3*HD + h, xvf)*gh;
        av1 += ldx(xvO, (size_t)sn*3*HD + HD + h, xvf)*gh;
        av2 += ldx(xvO, (size_t)sn*3*HD + 2*HD + h, xvf)*gh;
        md0 += mh*d0; md1 += mh*d1; md2 += mh*d2;
        sd0 += d0; sd1 += d1; sd2 += d2;
    }
    mdS[0][h]=md0; mdS[1][h]=md1; mdS[2][h]=md2;
    smS[h]=sm;
    xsS[h]=xs[(size_t)n*HD + h];
    __syncthreads();
    float a0=0,a1=0,a2=0, xw=0, sw=0;
    for (int k=0;k<128;++k){
        float w2 = Wv2[k*HD+h];
        a0 += mdS[0][k]*w2;
        a1 += mdS[1][k]*w2;
        a2 += mdS[2][k]*w2;
        xw += xsS[k]*Wsx[k*HD+h];
        sw += smS[k]*Wsa[k*HD+h];
    }
    float b2 = bv2[h];
    sumvC[(size_t)b*3*HD + h]        = av0 + a0 + b2*sd0;
    sumvC[(size_t)b*3*HD + HD + h]   = av1 + a1 + b2*sd1;
    sumvC[(size_t)b*3*HD + 2*HD + h] = av2 + a2 + b2*sd2;
    xscC[(size_t)b*HD + h] = xw + sw + bs[h];
}

// per-chunk layernorm + equivariant norm + gating + residual
__global__ __launch_bounds__(128)
void node_update_chunk(const float* __restrict__ xscC, const float* __restrict__ sumvC,
                       float* __restrict__ xs, const void* __restrict__ xvO,
                       void* __restrict__ xvN, int xvf,
                       const float* __restrict__ lng, const float* __restrict__ lnb,
                       const float* __restrict__ vsg, int addRes, int n0){
    __shared__ float red[4];
    __shared__ float red2[2];
    int b = blockIdx.x, h = threadIdx.x;
    int n = n0 + b;
    float xc = xscC[(size_t)b*HD + h];
    float s1 = xc, s2 = xc*xc;
#pragma unroll
    for (int off=1; off<64; off<<=1){ s1 += __shfl_xor(s1,off,64); s2 += __shfl_xor(s2,off,64); }
    int w = h >> 6;
    if ((h & 63) == 0){ red[w*2]=s1; red[w*2+1]=s2; }
    __syncthreads();
    s1 = red[0]+red[2]; s2 = red[1]+red[3];
    float mu = s1*(1.f/128.f);
    float var = fmaxf(s2*(1.f/128.f) - mu*mu, 0.f);
    float xn = (xc-mu)*rsqrtf(var+1e-5f)*lng[h] + lnb[h];

    float ov0 = ldx(xvO, (size_t)n*3*HD + h, xvf);
    float ov1 = ldx(xvO, (size_t)n*3*HD + HD + h, xvf);
    float ov2 = ldx(xvO, (size_t)n*3*HD + 2*HD + h, xvf);
    float v0 = ov0 + sumvC[(size_t)b*3*HD + h];
    float v1 = ov1 + sumvC[(size_t)b*3*HD + HD + h];
    float v2 = ov2 + sumvC[(size_t)b*3*HD + 2*HD + h];
    float q = v0*v0 + v1*v1 + v2*v2;
#pragma unroll
    for (int off=1; off<64; off<<=1) q += __shfl_xor(q,off,64);
    if ((h & 63) == 0) red2[w] = q;
    __syncthreads();
    q = fmaxf(red2[0] + red2[1], 0.f);
    float nrm = sqrtf(q*(1.f/128.f) + 1e-5f);
    float scale = vsg[h] * sigm_(xn) / nrm;
    float r0 = v0*scale, r1 = v1*scale, r2 = v2*scale;
    float nxs = silu_(xn);
    if (addRes){ nxs += xs[(size_t)n*HD+h]; r0 += ov0; r1 += ov1; r2 += ov2; }
    xs[(size_t)n*HD + h] = nxs;
    stx(xvN, (size_t)n*3*HD + h,        xvf, r0);
    stx(xvN, (size_t)n*3*HD + HD + h,   xvf, r1);
    stx(xvN, (size_t)n*3*HD + 2*HD + h, xvf, r2);
}

// per-node: P = xs@pcW+pcb, squash, pv norms -> u (plain stores, NO atomics)
__global__ __launch_bounds__(128)
void capsule_u(const float* __restrict__ xs, const void* __restrict__ xv, int xvf,
               const float* __restrict__ pcW, const float* __restrict__ pcb,
               const float* __restrict__ pvW, void* __restrict__ u, int uf){
    __shared__ float xsS[128];
    __shared__ float Pn[128];
    __shared__ float Xv[3][128];
    __shared__ float dots[48];
    __shared__ float pvn[16];
    __shared__ float capn2[8];
    int n = blockIdx.x, t = threadIdx.x;
    xsS[t] = xs[(size_t)n*HD + t];
    Xv[0][t] = ldx(xv, (size_t)n*3*HD + t, xvf);
    Xv[1][t] = ldx(xv, (size_t)n*3*HD + HD + t, xvf);
    Xv[2][t] = ldx(xv, (size_t)n*3*HD + 2*HD + t, xvf);
    __syncthreads();
    float p = pcb[t];
    for (int k=0;k<128;++k) p += xsS[k]*pcW[(size_t)k*HD + t];
    Pn[t] = p;
    __syncthreads();
    if (t < 48){
        int pp = t/3, c = t%3;
        float a = 0.f;
        for (int hh=0; hh<128; ++hh) a += Xv[c][hh]*pvW[hh*16+pp];
        dots[t] = a;
    }
    if (t < 8){
        float a = 0.f;
        for (int d=0; d<16; ++d){ float x = Pn[t*16+d]; a += x*x; }
        capn2[t] = a;
    }
    __syncthreads();
    if (t < 16){
        float a = dots[t*3]*dots[t*3] + dots[t*3+1]*dots[t*3+1] + dots[t*3+2]*dots[t*3+2];
        pvn[t] = sqrtf(a + 1e-9f);
    }
    __syncthreads();
    int cap = t >> 4, d = t & 15;
    float n2 = capn2[cap];
    float pcv = Pn[t] * (n2/(1.f+n2)) * rsqrtf(n2 + 1e-9f);
    stx(u, (size_t)n*HD + t, uf, pcv + pvn[d]);
}

__global__ void pool_u(const int* __restrict__ gptr, const void* __restrict__ u, int uf,
                       float* __restrict__ U){
    int b = blockIdx.x, h = threadIdx.x;
    int s = gptr[b], e = gptr[b+1];
    s = min(max(s,0), NN); e = min(max(e,0), NN);
    float a = 0.f;
    for (int n=s; n<e; ++n) a += ldx(u, (size_t)n*HD + h, uf);
    U[b*HD + h] = a;
}

// per-graph head; FLOAT32 output (reference returns fp32); non-finite -> 999 sentinel
__global__ void graph_head(const float* __restrict__ U, const float* __restrict__ sW,
                           const float* __restrict__ aW, const float* __restrict__ ab,
                           const float* __restrict__ pW1, const float* __restrict__ pb1,
                           const float* __restrict__ pg1, const float* __restrict__ pbe1,
                           const float* __restrict__ pW2, const float* __restrict__ pb2,
                           const float* __restrict__ pg2, const float* __restrict__ pbe2,
                           const float* __restrict__ pW3, const float* __restrict__ pb3,
                           float* __restrict__ out){
    __shared__ float Ub[128];
    __shared__ float pooled[2048];  // [p][c][e] = [8][8][32]
    __shared__ float vv[256];       // [c][e]
    __shared__ float bbs[64], ccs[64];
    __shared__ float lg[8], aws[8];
    __shared__ float wcs[32];
    __shared__ float h1[64], h2[32];
    int b = blockIdx.x, t = threadIdx.x;
    if (t < 128) Ub[t] = U[b*HD + t];
    __syncthreads();
#pragma unroll
    for (int j=0;j<8;++j){
        int o = t + 256*j;
        int p = o >> 8, c = (o >> 5) & 7, e = o & 31;
        float a = 0.f;
#pragma unroll
        for (int d=0; d<16; ++d) a += Ub[p*16+d]*sW[((p*16+d)*8+c)*32+e];
        pooled[o] = a;
    }
    __syncthreads();
    {
        float s = 0.f;
        for (int p=0;p<8;++p) s += pooled[p*256 + t];
        s *= 0.125f;
        float n2 = s*s;
#pragma unroll
        for (int off=1; off<32; off<<=1) n2 += __shfl_xor(n2,off,32);
        vv[t] = s*(n2/(1.f+n2))*rsqrtf(n2+1e-9f);
    }
    __syncthreads();
    if (t < 64){
        int p = t>>3, c = t&7;
        float a = 0.f;
        for (int e=0;e<32;++e) a += pooled[p*256+c*32+e]*vv[c*32+e];
        bbs[t] = a;
    }
    __syncthreads();
    if (t < 64){
        int p = t>>3;
        float mx = -1e30f;
        for (int j=0;j<8;++j) mx = fmaxf(mx, bbs[p*8+j]);
        float sum = 0.f;
        for (int j=0;j<8;++j) sum += __expf(bbs[p*8+j]-mx);
        ccs[t] = __expf(bbs[t]-mx)/sum;
    }
    __syncthreads();
    {
        int c = t>>5;
        float s = 0.f;
        for (int p=0;p<8;++p) s += ccs[p*8+c]*pooled[p*256 + t];
        float n2 = s*s;
#pragma unroll
        for (int off=1; off<32; off<<=1) n2 += __shfl_xor(n2,off,32);
        vv[t] = s*(n2/(1.f+n2))*rsqrtf(n2+1e-9f);
    }
    __syncthreads();
    if (t < 8){
        float a = 0.f;
        for (int j=0;j<16;++j) a += vv[t*32+j]*aW[j];
        lg[t] = a + ab[0];
    }
    __syncthreads();
    if (t < 8){
        float mx = -1e30f;
        for (int j=0;j<8;++j) mx = fmaxf(mx, lg[j]);
        float sum = 0.f;
        for (int j=0;j<8;++j) sum += __expf(lg[j]-mx);
        aws[t] = __expf(lg[t]-mx)/sum;
    }
    __syncthreads();
    if (t < 32){
        float a = 0.f;
        for (int c=0;c<8;++c) a += aws[c]*vv[c*32+t];
        wcs[t] = a;
    }
    __syncthreads();
    if (t < 64){
        float a = 0.f;
        for (int e=0;e<32;++e) a += wcs[e]*pW1[e*64+t];
        h1[t] = silu_((a+pb1[t])*pg1[t]+pbe1[t]);
    }
    __syncthreads();
    if (t < 32){
        float a = 0.f;
        for (int j=0;j<64;++j) a += h1[j]*pW2[j*32+t];
        h2[t] = silu_((a+pb2[t])*pg2[t]+pbe2[t]);
    }
    __syncthreads();
    if (t == 0){
        float a = 0.f;
        for (int j=0;j<32;++j) a += h2[j]*pW3[j];
        a += pb3[0];
        if (!finite_(a)) a = 999.f;   // NaN tripwire
        out[b] = a;
    }
}

__global__ void sentinel_k(float* __restrict__ out, float v){
    out[threadIdx.x] = v;
}

// ---------------- host side ----------------
extern "C" void kernel_launch(void* const* d_in, const int* in_sizes, int n_in,
                              void* d_out, int out_size, void* d_ws, size_t ws_size,
                              hipStream_t stream)
{
    (void)in_sizes; (void)n_in; (void)out_size;
    const float* x    = (const float*)d_in[0];
    const float* eat  = (const float*)d_in[1];
    const float* pos  = (const float*)d_in[2];
    const int*  eidx  = (const int*)d_in[3];
    const int*  batch = (const int*)d_in[4];
    const float* neW1=(const float*)d_in[5],  *neb1=(const float*)d_in[6],
               * neg1=(const float*)d_in[7],  *nebe1=(const float*)d_in[8];
    const float* neW2=(const float*)d_in[9],  *neb2=(const float*)d_in[10],
               * neg2=(const float*)d_in[11], *nebe2=(const float*)d_in[12];
    const float* eeW1=(const float*)d_in[13], *eeb1=(const float*)d_in[14];
    const float* eeW2=(const float*)d_in[15], *eeb2=(const float*)d_in[16];
    const float* ivW =(const float*)d_in[17], *ivb =(const float*)d_in[18];
    const float* cWma=(const float*)d_in[19], *cWmb=(const float*)d_in[20],
               * cWme=(const float*)d_in[21], *cbm =(const float*)d_in[22];
    const float* cWsx=(const float*)d_in[23], *cWsa=(const float*)d_in[24],
               * cbs =(const float*)d_in[25];
    const float* cWv1=(const float*)d_in[26], *cbv1=(const float*)d_in[27],
               * cWv2=(const float*)d_in[28], *cbv2=(const float*)d_in[29];
    const float* lng =(const float*)d_in[30], *lnb =(const float*)d_in[31],
               * vsg =(const float*)d_in[32];
    const float* pcW =(const float*)d_in[33], *pcb =(const float*)d_in[34];
    const float* pvW =(const float*)d_in[35];
    const float* sW  =(const float*)d_in[36];
    const float* aW  =(const float*)d_in[37], *ab  =(const float*)d_in[38];
    const float* pW1 =(const float*)d_in[39], *pb1 =(const float*)d_in[40],
               * pg1 =(const float*)d_in[41], *pbe1=(const float*)d_in[42];
    const float* pW2 =(const float*)d_in[43], *pb2 =(const float*)d_in[44],
               * pg2 =(const float*)d_in[45], *pbe2=(const float*)d_in[46];
    const float* pW3 =(const float*)d_in[47], *pb3 =(const float*)d_in[48];

    const int* src = eidx;
    const int* dst = eidx + NE;

    // ---- precision tiers (host decision on constant ws_size; same work every call) ----
    auto tier_total = [&](int esz, int vsz, int asz)->size_t{
        auto al = [](size_t b){ return (b + 255) & ~(size_t)255; };
        size_t t = 0;
        t += 2*al((size_t)EC_MAX*HD*esz);          // bufA, bufB
        t += al((size_t)CN*HD*4);                  // bnc
        t += al((size_t)CN*3*HD*4);                // sumvC
        t += al((size_t)CN*HD*4);                  // xscC
        t += al((size_t)NN*HD*4);                  // xs
        t += 2*al((size_t)NN*3*HD*vsz);            // xvA, xvB
        t += al((size_t)NN*HD*asz);                // An (also u)
        t += al((size_t)NN*3*4);                   // posf
        t += al((size_t)NB*HD*4);                  // Ubuf
        t += al((size_t)(NN+1)*4) + al((size_t)NN*4) + al((size_t)NE*4)
           + al((size_t)(NB+1)*4);
        return t;
    };
    int esz = 2, vsz = 2, asz = 2;
    if (tier_total(4,4,4) <= ws_size){ esz=4; vsz=4; asz=4; }
    else if (tier_total(4,4,2) <= ws_size){ esz=4; vsz=4; }
    else if (tier_total(4,2,2) <= ws_size){ esz=4; }
    const int ebf = (esz==2), xvf = (vsz==2), anf = (asz==2);

    char* wp = (char*)d_ws;
    auto alloc = [&](size_t bytes)->char*{
        char* p = wp;
        wp += (bytes + 255) & ~(size_t)255;
        return p;
    };
    void*  bufA  = (void*) alloc((size_t)EC_MAX*HD*esz);
    void*  bufB  = (void*) alloc((size_t)EC_MAX*HD*esz);
    float* bnc   = (float*)alloc((size_t)CN*HD*4);
    float* sumvC = (float*)alloc((size_t)CN*3*HD*4);
    float* xscC  = (float*)alloc((size_t)CN*HD*4);
    float* xs    = (float*)alloc((size_t)NN*HD*4);
    void*  xvA   = (void*) alloc((size_t)NN*3*HD*vsz);
    void*  xvB   = (void*) alloc((size_t)NN*3*HD*vsz);
    void*  An    = (void*) alloc((size_t)NN*HD*asz);
    float* posf  = (float*)alloc((size_t)NN*3*4);
    float* Ubuf  = (float*)alloc((size_t)NB*HD*4);
    int* rowptr  = (int*)alloc((size_t)(NN+1)*4);
    int* cnt     = (int*)alloc((size_t)NN*4);
    int* elist   = (int*)alloc((size_t)NE*4);
    int* gptr    = (int*)alloc((size_t)(NB+1)*4);
    size_t used  = (size_t)(wp - (char*)d_ws);

    if (used > ws_size){
        // report ws size: out = -(1 + wsMB); never aliases 0
        sentinel_k<<<1, NB, 0, stream>>>((float*)d_out, -1.f - (float)(ws_size >> 20));
        return;
    }
    float* tmpF = (float*)xvB;   // NN*HD fp32 scratch fits in xvB
    void*  ubuf = An;            // An dead after layers; u stored with anf dtype

    // ---- CSR by dst + gptr + posf ----
    hipMemsetAsync(cnt, 0, (size_t)NN*4, stream);
    hist_kernel<<<(NE+255)/256, 256, 0, stream>>>(dst, cnt, NE, NN);
    scan_kernel<<<1, 256, 0, stream>>>(cnt, rowptr, NN);
    hipMemsetAsync(cnt, 0, (size_t)NN*4, stream);
    fill_kernel<<<(NE+255)/256, 256, 0, stream>>>(dst, rowptr, cnt, elist, NE);
    gptr_kernel<<<(NN+255)/256, 256, 0, stream>>>(batch, gptr);
    posf_kernel<<<(NN*3+255)/256, 256, 0, stream>>>(pos, posf);

    const int GN = (NN+63)/64;
    const int GE = (EC_MAX+63)/64;
    const int GC = (CN+63)/64;

    // ---- node embeddings ----
    gemmk<M_BNSILU,0><<<GN,256,0,stream>>>(x, 0, neW1, neb1, neg1, nebe1,
        nullptr,0,nullptr,nullptr, nullptr,0,nullptr, nullptr,0,0, tmpF, 0, NN, 92);
    gemmk<M_BNSILU,0><<<GN,256,0,stream>>>(tmpF, 0, neW2, neb2, neg2, nebe2,
        nullptr,0,nullptr,nullptr, nullptr,0,nullptr, nullptr,0,0, xs, 0, NN, 128);
    gemmk<M_BIAS,0><<<GN,256,0,stream>>>(xs, 0, ivW, ivb, nullptr, nullptr,
        nullptr,0,nullptr,nullptr, nullptr,0,nullptr, nullptr,0,0, tmpF, 0, NN, 128);
    xv_init<<<NN, 128, 0, stream>>>(tmpF, posf, xvA, xvf);

    // ---- message-passing layers (xv double-buffered) ----
    void* xvO = xvA;
    void* xvN = xvB;
    for (int l=0; l<3; ++l){
        const float* Wma = cWma + (size_t)l*HD*HD;
        const float* Wmb = cWmb + (size_t)l*HD*HD;
        const float* Wme = cWme + (size_t)l*HD*HD;
        const float* bm  = cbm  + (size_t)l*HD;
        const float* Wsx = cWsx + (size_t)l*HD*HD;
        const float* Wsa = cWsa + (size_t)l*HD*HD;
        const float* bs  = cbs  + (size_t)l*HD;
        const float* Wv1 = cWv1 + (size_t)l*HD*HD;
        const float* bv1 = cbv1 + (size_t)l*HD;
        const float* Wv2 = cWv2 + (size_t)l*HD*HD;
        const float* bv2 = cbv2 + (size_t)l*HD;

        gemmk<M_PLAIN,0><<<GN,256,0,stream>>>(xs, 0, Wma, nullptr,nullptr,nullptr,
            nullptr,0,nullptr,nullptr, nullptr,0,nullptr, nullptr,0,0, An, anf, NN, 128);

        for (int c=0; c<NCH; ++c){
            int n0 = c*CN, n1 = n0+CN;
            gemmk<M_PLAIN,0><<<GC,256,0,stream>>>(xs + (size_t)n0*HD, 0, Wmb,
                nullptr,nullptr,nullptr, nullptr,0,nullptr,nullptr, nullptr,0,nullptr,
                nullptr,0,0, bnc, 0, CN, 128);
            gemmk<M_SILU,1><<<GE,256,0,stream>>>(eat, 0, eeW1, eeb1, nullptr,nullptr,
                elist, 0, nullptr,nullptr, nullptr,0,nullptr, rowptr, n0, n1, bufA, ebf, EC_MAX, 41);
            gemmk<M_SILU,0><<<GE,256,0,stream>>>(bufA, ebf, eeW2, eeb2, nullptr,nullptr,
                nullptr, 0, nullptr,nullptr, nullptr,0,nullptr, rowptr, n0, n1, bufB, ebf, EC_MAX, 128);
            gemmk<M_MSG,0><<<GE,256,0,stream>>>(bufB, ebf, Wme, bm, nullptr,nullptr,
                elist, n0, src, dst, An, anf, bnc, rowptr, n0, n1, bufA, ebf, EC_MAX, 128);
            gemmk<M_BIAS,0><<<GE,256,0,stream>>>(bufA, ebf, Wv1, bv1, nullptr,nullptr,
                nullptr, 0, nullptr,nullptr, nullptr,0,nullptr, rowptr, n0, n1, bufB, ebf, EC_MAX, 128);
            scatter_fused<<<CN,128,0,stream>>>(rowptr, elist, src, posf, bufA, bufB, ebf,
                                               xvO, xvf, xs, Wv2, bv2, Wsx, Wsa, bs,
                                               sumvC, xscC, n0);
            node_update_chunk<<<CN,128,0,stream>>>(xscC, sumvC, xs, xvO, xvN, xvf,
                                                   lng + (size_t)l*HD, lnb + (size_t)l*HD,
                                                   vsg + (size_t)l*HD, l>0 ? 1 : 0, n0);
        }
        void* t = xvO; xvO = xvN; xvN = t;
    }
    // final xv in xvO

    // ---- capsules & head (no FP atomics) ----
    capsule_u<<<NN, 128, 0, stream>>>(xs, xvO, xvf, pcW, pcb, pvW, ubuf, anf);
    pool_u<<<NB, 128, 0, stream>>>(gptr, ubuf, anf, Ubuf);
    graph_head<<<NB, 256, 0, stream>>>(Ubuf, sW, aW, ab,
                                       pW1, pb1, pg1, pbe1,
                                       pW2, pb2, pg2, pbe2,
                                       pW3, pb3, (float*)d_out);
}

// Round 10
// 8270.020 us; speedup vs baseline: 1.3320x; 1.3320x over previous
//
#include <hip/hip_runtime.h>
#include <hip/hip_bf16.h>
#include <math.h>

#define NN 50000
#define NE 400000
#define HD 128
#define NB 64
#define NCH 8
#define CN 6250          // nodes per chunk
#define ECM 53248        // max edges per chunk (mean 50000, sigma~209; +15.5 sigma, 64-mult)
#define NPB 8            // nodes per block in su_fused

typedef __hip_bfloat16 bf16;
typedef __attribute__((ext_vector_type(4))) unsigned short us4;

__device__ __forceinline__ float sigm_(float x){ return 1.f/(1.f+__expf(-x)); }
__device__ __forceinline__ float silu_(float x){ return x*sigm_(x); }
__device__ __forceinline__ float bf2f(bf16 x){ return __bfloat162float(x); }
__device__ __forceinline__ float bu2f(unsigned short u){ return __uint_as_float(((unsigned)u)<<16); }
__device__ __forceinline__ unsigned short f2bu(float f){
    bf16 h = __float2bfloat16(f);
    return *reinterpret_cast<unsigned short*>(&h);
}
__device__ __forceinline__ bool finite_(float v){ return fabsf(v) <= 1e37f; }

enum { M_PLAIN=0, M_BIAS, M_BNSILU };

// ---------------- generic tiled GEMM: C[M,128] = epilogue(A[M,K] @ W[K,128]) ----------
// A fp32. owf: 1 = bf16 out, 0 = fp32 out.
template<int MODE>
__global__ __launch_bounds__(256)
void gemmk(const float* __restrict__ A, const float* __restrict__ W,
           const float* __restrict__ bias, const float* __restrict__ gg,
           const float* __restrict__ be, void* __restrict__ Cv, int owf, int M, int K)
{
    const int row0 = blockIdx.x * 64;
    if (row0 >= M) return;
    __shared__ float As[32][68];
    __shared__ float Ws[32][128];
    const int tid = threadIdx.x;
    const int tx = tid & 15, ty = tid >> 4;
    const int col0 = tx*8;
    float acc[4][8];
#pragma unroll
    for (int r=0;r<4;++r)
#pragma unroll
        for (int j=0;j<8;++j) acc[r][j]=0.f;
    const int mload = tid >> 2;
    const int kload = (tid & 3) << 3;
    const int grow = row0 + mload;
    const bool rv = grow < M;

    for (int k0 = 0; k0 < K; k0 += 32) {
        if (rv && ((K & 3) == 0) && (k0 + kload + 8 <= K)) {
            const float* ap = A + (size_t)grow*K + k0 + kload;
            float4 v0 = *(const float4*)ap;
            float4 v1 = *(const float4*)(ap+4);
            As[kload+0][mload]=v0.x; As[kload+1][mload]=v0.y;
            As[kload+2][mload]=v0.z; As[kload+3][mload]=v0.w;
            As[kload+4][mload]=v1.x; As[kload+5][mload]=v1.y;
            As[kload+6][mload]=v1.z; As[kload+7][mload]=v1.w;
        } else {
#pragma unroll
            for (int j=0;j<8;++j){
                int kg = k0 + kload + j;
                As[kload+j][mload] = (rv && kg<K) ? A[(size_t)grow*K+kg] : 0.f;
            }
        }
        if (k0 + 32 <= K) {
#pragma unroll
            for (int j=0;j<4;++j){
                int el = (tid + j*256)*4;
                int kk = el >> 7, col = el & 127;
                *(float4*)&Ws[kk][col] = *(const float4*)&W[(size_t)(k0+kk)*HD + col];
            }
        } else {
#pragma unroll
            for (int j=0;j<16;++j){
                int el = tid*16 + j;
                int kk = el >> 7, col = el & 127;
                int kg = k0 + kk;
                Ws[kk][col] = (kg < K) ? W[(size_t)kg*HD + col] : 0.f;
            }
        }
        __syncthreads();
#pragma unroll
        for (int k=0;k<32;++k){
            float4 a4 = *(const float4*)&As[k][ty*4];
            float4 w0 = *(const float4*)&Ws[k][col0];
            float4 w1 = *(const float4*)&Ws[k][col0+4];
            float av[4] = {a4.x,a4.y,a4.z,a4.w};
            float wv[8] = {w0.x,w0.y,w0.z,w0.w,w1.x,w1.y,w1.z,w1.w};
#pragma unroll
            for (int r=0;r<4;++r)
#pragma unroll
                for (int j=0;j<8;++j) acc[r][j] += av[r]*wv[j];
        }
        __syncthreads();
    }
#pragma unroll
    for (int r=0;r<4;++r){
        int orow = row0 + ty*4 + r;
        if (orow >= M) continue;
        float o[8];
#pragma unroll
        for (int j=0;j<8;++j) o[j]=acc[r][j];
        if constexpr (MODE==M_BIAS || MODE==M_BNSILU){
#pragma unroll
            for (int j=0;j<8;++j) o[j] += bias[col0+j];
        }
        if constexpr (MODE==M_BNSILU){
#pragma unroll
            for (int j=0;j<8;++j) o[j] = silu_(o[j]*gg[col0+j] + be[col0+j]);
        }
        if (owf){
            bf16* C = (bf16*)Cv;
#pragma unroll
            for (int j=0;j<8;++j) C[(size_t)orow*HD+col0+j] = __float2bfloat16(o[j]);
        } else {
            float* C = (float*)Cv;
            float4* cp = (float4*)&C[(size_t)orow*HD + col0];
            cp[0] = make_float4(o[0],o[1],o[2],o[3]);
            cp[1] = make_float4(o[4],o[5],o[6],o[7]);
        }
    }
}

// ---------------- fused edge pipeline for one chunk ----------------
// rows = CSR positions [cbase, cbase+Ml): e1=silu(EAT[elist]@W1+b1); ea=silu(e1@W2+b2);
// m=silu(ea@Wme+An[srcp]+Bn[dstp]+bm) -> outM; g1=m@Wv1+bv1 -> outG.
__global__ __launch_bounds__(256)
void edge_pipe(const float* __restrict__ eat,
               const int* __restrict__ elist, const int* __restrict__ srcp,
               const int* __restrict__ dstp,
               const float* __restrict__ W1, const float* __restrict__ b1,
               const float* __restrict__ W2, const float* __restrict__ b2,
               const float* __restrict__ Wme, const float* __restrict__ bm,
               const bf16* __restrict__ An, const bf16* __restrict__ Bn,
               const float* __restrict__ Wv1, const float* __restrict__ bv1,
               const int* __restrict__ rp, int rn0, int rn1,
               bf16* __restrict__ outM, bf16* __restrict__ outG)
{
    __shared__ float Ws[32][128];
    __shared__ __align__(16) unsigned short T1[128][72];
    __shared__ __align__(16) unsigned short T2[128][72];
    float (*As)[68] = (float(*)[68])T2;   // alias: As only live in G1, T2 written in G2

    const int cbase = rp[rn0];
    const int Ml = min(ECM, max(rp[rn1]-cbase, 0));
    const int row0 = blockIdx.x*64;
    if (row0 >= Ml) return;
    const int tid=threadIdx.x, tx=tid&15, ty=tid>>4;
    const int mload=tid>>2, kload=(tid&3)<<3;
    const int grow=row0+mload;
    const bool rv = grow<Ml;
    const int col0=tx*8;
    float acc[4][8];

    // ---------- G1: K=41 ----------
#pragma unroll
    for (int r=0;r<4;++r)
#pragma unroll
        for (int j=0;j<8;++j) acc[r][j]=0.f;
    int arow=0;
    if (rv){ int e=elist[cbase+grow]; arow=min(max(e,0),NE-1); }
    for (int k0=0;k0<41;k0+=32){
#pragma unroll
        for (int j=0;j<8;++j){
            int kg=k0+kload+j;
            As[kload+j][mload] = (rv&&kg<41)? eat[(size_t)arow*41+kg] : 0.f;
        }
#pragma unroll
        for (int j=0;j<16;++j){
            int el=tid*16+j;
            int kk=el>>7, col=el&127;
            int kg=k0+kk;
            Ws[kk][col] = (kg<41)? W1[(size_t)kg*HD+col] : 0.f;
        }
        __syncthreads();
#pragma unroll
        for (int k=0;k<32;++k){
            float4 a4=*(const float4*)&As[k][ty*4];
            float4 w0=*(const float4*)&Ws[k][col0];
            float4 w1=*(const float4*)&Ws[k][col0+4];
            float av[4]={a4.x,a4.y,a4.z,a4.w};
            float wv[8]={w0.x,w0.y,w0.z,w0.w,w1.x,w1.y,w1.z,w1.w};
#pragma unroll
            for (int r=0;r<4;++r)
#pragma unroll
                for (int j=0;j<8;++j) acc[r][j]+=av[r]*wv[j];
        }
        __syncthreads();
    }
#pragma unroll
    for (int r=0;r<4;++r)
#pragma unroll
        for (int j=0;j<8;++j)
            T1[col0+j][ty*4+r] = f2bu(silu_(acc[r][j]+b1[col0+j]));
    __syncthreads();

    // ---------- G2/G3/G4: K=128 phases ----------
    for (int ph=0; ph<3; ++ph){
        const float* Wp = (ph==0)? W2 : (ph==1)? Wme : Wv1;
        const unsigned short (*Tin)[72] = (ph==1)? (const unsigned short(*)[72])T2
                                                 : (const unsigned short(*)[72])T1;
#pragma unroll
        for (int r=0;r<4;++r)
#pragma unroll
            for (int j=0;j<8;++j) acc[r][j]=0.f;
        for (int k0=0;k0<128;k0+=32){
#pragma unroll
            for (int j=0;j<4;++j){
                int el=(tid+j*256)*4;
                int kk=el>>7, col=el&127;
                *(float4*)&Ws[kk][col] = *(const float4*)&Wp[(size_t)(k0+kk)*HD+col];
            }
            __syncthreads();
#pragma unroll
            for (int k=0;k<32;++k){
                us4 a4=*(const us4*)&Tin[k0+k][ty*4];
                float4 w0=*(const float4*)&Ws[k][col0];
                float4 w1=*(const float4*)&Ws[k][col0+4];
                float av[4]={bu2f(a4[0]),bu2f(a4[1]),bu2f(a4[2]),bu2f(a4[3])};
                float wv[8]={w0.x,w0.y,w0.z,w0.w,w1.x,w1.y,w1.z,w1.w};
#pragma unroll
                for (int r=0;r<4;++r)
#pragma unroll
                    for (int j=0;j<8;++j) acc[r][j]+=av[r]*wv[j];
            }
            __syncthreads();
        }
        if (ph==0){          // ea -> T2
#pragma unroll
            for (int r=0;r<4;++r)
#pragma unroll
                for (int j=0;j<8;++j)
                    T2[col0+j][ty*4+r] = f2bu(silu_(acc[r][j]+b2[col0+j]));
        } else if (ph==1){   // m -> outM + T1
#pragma unroll
            for (int r=0;r<4;++r){
                int orow=row0+ty*4+r;
                bool ov = orow<Ml;
                int p = cbase + (ov?orow:0);
                int se = srcp[p]; se=min(max(se,0),NN-1);
                int de = dstp[p]; de=min(max(de,0),NN-1);
                const us4* ap=(const us4*)&An[(size_t)se*HD+col0];
                const us4* bp=(const us4*)&Bn[(size_t)de*HD+col0];
                us4 a0v=ap[0], a1v=ap[1], b0v=bp[0], b1v=bp[1];
                float o[8];
#pragma unroll
                for (int j=0;j<4;++j)
                    o[j]=silu_(acc[r][j]+bm[col0+j]+bu2f(a0v[j])+bu2f(b0v[j]));
#pragma unroll
                for (int j=0;j<4;++j)
                    o[4+j]=silu_(acc[r][4+j]+bm[col0+4+j]+bu2f(a1v[j])+bu2f(b1v[j]));
                if (ov){
                    us4 lo, hi;
#pragma unroll
                    for (int j=0;j<4;++j){ lo[j]=f2bu(o[j]); hi[j]=f2bu(o[4+j]); }
                    *(us4*)&outM[(size_t)orow*HD+col0] = lo;
                    *(us4*)&outM[(size_t)orow*HD+col0+4] = hi;
                }
#pragma unroll
                for (int j=0;j<8;++j) T1[col0+j][ty*4+r]=f2bu(o[j]);
            }
        } else {             // g1 -> outG
#pragma unroll
            for (int r=0;r<4;++r){
                int orow=row0+ty*4+r;
                if (orow>=Ml) continue;
                us4 lo, hi;
#pragma unroll
                for (int j=0;j<4;++j){
                    lo[j]=f2bu(acc[r][j]+bv1[col0+j]);
                    hi[j]=f2bu(acc[r][4+j]+bv1[col0+4+j]);
                }
                *(us4*)&outG[(size_t)orow*HD+col0] = lo;
                *(us4*)&outG[(size_t)orow*HD+col0+4] = hi;
            }
        }
        __syncthreads();
    }
}

// ---------------- fused scatter + GEMVs + layernorm/update, NPB nodes per block ------
__global__ __launch_bounds__(128)
void su_fused(const int* __restrict__ rp, const int* __restrict__ srcp,
              const float* __restrict__ pos,
              const bf16* __restrict__ mB, const bf16* __restrict__ gB,
              const float* __restrict__ xvO, float* __restrict__ xvN,
              float* __restrict__ xs,
              const float* __restrict__ Wv2, const float* __restrict__ bv2,
              const float* __restrict__ Wsx, const float* __restrict__ Wsa,
              const float* __restrict__ bs,
              const float* __restrict__ lng, const float* __restrict__ lnb,
              const float* __restrict__ vsg, int addRes, int n0, int n1)
{
    __shared__ float mdS[NPB][3][128];
    __shared__ float smS[NPB][128];
    __shared__ float xsS[NPB][128];
    __shared__ float red[4];
    __shared__ float red2[2];
    const int h = threadIdx.x;
    const int base = n0 + blockIdx.x*NPB;
    const int cbase = rp[n0];
    float av0[NPB],av1[NPB],av2[NPB],sd0[NPB],sd1[NPB],sd2[NPB];
#pragma unroll
    for (int i=0;i<NPB;++i){
        int n = base+i;
        bool valid = n < n1;
        float sm=0,a0=0,a1=0,a2=0,m0=0,m1=0,m2=0,d0s=0,d1s=0,d2s=0;
        if (valid){
            int p0=rp[n], p1=rp[n+1];
            float px0=pos[n*3],px1=pos[n*3+1],px2=pos[n*3+2];
            for (int p=p0;p<p1;++p){
                int ii=p-cbase; if ((unsigned)ii>=(unsigned)ECM) break;
                float mh=bf2f(mB[(size_t)ii*HD+h]);
                float gh=bf2f(gB[(size_t)ii*HD+h]);
                int sn=srcp[p]; sn=min(max(sn,0),NN-1);
                float d0=px0-pos[sn*3], d1=px1-pos[sn*3+1], d2=px2-pos[sn*3+2];
                sm+=mh;
                a0+=xvO[(size_t)sn*3*HD+h]*gh;
                a1+=xvO[(size_t)sn*3*HD+HD+h]*gh;
                a2+=xvO[(size_t)sn*3*HD+2*HD+h]*gh;
                m0+=mh*d0; m1+=mh*d1; m2+=mh*d2;
                d0s+=d0; d1s+=d1; d2s+=d2;
            }
        }
        mdS[i][0][h]=m0; mdS[i][1][h]=m1; mdS[i][2][h]=m2;
        smS[i][h]=sm;
        xsS[i][h]= valid ? xs[(size_t)n*HD+h] : 0.f;
        av0[i]=a0; av1[i]=a1; av2[i]=a2; sd0[i]=d0s; sd1[i]=d1s; sd2[i]=d2s;
    }
    __syncthreads();
    float g0[NPB],g1v[NPB],g2[NPB],xw[NPB],sw[NPB];
#pragma unroll
    for (int i=0;i<NPB;++i){ g0[i]=0;g1v[i]=0;g2[i]=0;xw[i]=0;sw[i]=0; }
    for (int k=0;k<HD;++k){
        float w2=Wv2[k*HD+h], wx=Wsx[k*HD+h], wa=Wsa[k*HD+h];
#pragma unroll
        for (int i=0;i<NPB;++i){
            g0[i]+=mdS[i][0][k]*w2;
            g1v[i]+=mdS[i][1][k]*w2;
            g2[i]+=mdS[i][2][k]*w2;
            xw[i]+=xsS[i][k]*wx;
            sw[i]+=smS[i][k]*wa;
        }
    }
    const float b2v=bv2[h], bsv=bs[h], lgv=lng[h], lbv=lnb[h], vgv=vsg[h];
    const int w = h >> 6;
    for (int i=0;i<NPB;++i){
        int n = base+i;
        bool valid = n < n1;
        float xc = xw[i]+sw[i]+bsv;
        float s1=xc, s2=xc*xc;
#pragma unroll
        for (int off=1; off<64; off<<=1){ s1+=__shfl_xor(s1,off,64); s2+=__shfl_xor(s2,off,64); }
        if ((h&63)==0){ red[w*2]=s1; red[w*2+1]=s2; }
        __syncthreads();
        s1=red[0]+red[2]; s2=red[1]+red[3];
        float mu=s1*(1.f/128.f);
        float var=fmaxf(s2*(1.f/128.f)-mu*mu, 0.f);
        float xn=(xc-mu)*rsqrtf(var+1e-5f)*lgv+lbv;
        float ov0=0,ov1=0,ov2=0;
        if (valid){
            ov0=xvO[(size_t)n*3*HD+h];
            ov1=xvO[(size_t)n*3*HD+HD+h];
            ov2=xvO[(size_t)n*3*HD+2*HD+h];
        }
        float v0=ov0+av0[i]+g0[i]+b2v*sd0[i];
        float v1=ov1+av1[i]+g1v[i]+b2v*sd1[i];
        float v2=ov2+av2[i]+g2[i]+b2v*sd2[i];
        float q=v0*v0+v1*v1+v2*v2;
#pragma unroll
        for (int off=1; off<64; off<<=1) q+=__shfl_xor(q,off,64);
        if ((h&63)==0) red2[w]=q;
        __syncthreads();
        q=fmaxf(red2[0]+red2[1], 0.f);
        float nrm=sqrtf(q*(1.f/128.f)+1e-5f);
        float scale=vgv*sigm_(xn)/nrm;
        float r0=v0*scale, r1=v1*scale, r2=v2*scale;
        float nxs=silu_(xn);
        if (addRes){ nxs+=xsS[i][h]; r0+=ov0; r1+=ov1; r2+=ov2; }
        if (valid){
            xs[(size_t)n*HD+h]=nxs;
            xvN[(size_t)n*3*HD+h]=r0;
            xvN[(size_t)n*3*HD+HD+h]=r1;
            xvN[(size_t)n*3*HD+2*HD+h]=r2;
        }
        __syncthreads();
    }
}

// ---------------- CSR build ----------------
__global__ void hist_kernel(const int* __restrict__ idx, int* __restrict__ cnt, int n, int nb){
    int i = blockIdx.x*256 + threadIdx.x;
    if (i < n){
        int v = idx[i]; v = min(max(v,0), nb-1);
        atomicAdd(&cnt[v], 1);
    }
}

__global__ void scan_kernel(const int* __restrict__ cnt, int* __restrict__ out, int n){
    __shared__ int sums[256];
    int t = threadIdx.x;
    int chunk = (n + 255) / 256;
    int lo = t*chunk, hi = lo+chunk; if (hi > n) hi = n; if (lo > n) lo = n;
    int s = 0;
    for (int i=lo;i<hi;++i) s += cnt[i];
    sums[t] = s;
    __syncthreads();
    if (t==0){ int run=0; for (int i=0;i<256;++i){ int v=sums[i]; sums[i]=run; run+=v; } }
    __syncthreads();
    int run = sums[t];
    for (int i=lo;i<hi;++i){ out[i]=run; run+=cnt[i]; }
    if (hi == n) out[n] = run;
}

__global__ void fill_kernel(const int* __restrict__ src, const int* __restrict__ dst,
                            const int* __restrict__ rowptr, int* __restrict__ cur,
                            int* __restrict__ elist, int* __restrict__ srcp,
                            int* __restrict__ dstp, int n){
    int e = blockIdx.x*256 + threadIdx.x;
    if (e < n){
        int d = dst[e]; d = min(max(d,0), NN-1);
        int slot = atomicAdd(&cur[d], 1);
        int p = rowptr[d] + slot;
        if (p >= 0 && p < NE){
            elist[p] = e;
            int s = src[e];
            srcp[p] = min(max(s,0), NN-1);
            dstp[p] = d;
        }
    }
}

__global__ void gptr_kernel(const int* __restrict__ batch, int* __restrict__ gptr){
    int n = blockIdx.x*256 + threadIdx.x;
    if (n >= NN) return;
    int b = batch[n]; b = min(max(b,0), NB-1);
    if (n == 0){
        for (int g=0; g<=b; ++g) gptr[g] = 0;
    } else {
        int bp = batch[n-1]; bp = min(max(bp,0), NB-1);
        for (int g=bp+1; g<=b; ++g) gptr[g] = n;
    }
    if (n == NN-1){
        for (int g=b+1; g<=NB; ++g) gptr[g] = NN;
    }
}

// xv[n][c][h] = xw[n][h] * pos[n][c]  (fp32)
__global__ void xv_init(const float* __restrict__ xw, const float* __restrict__ pos,
                        float* __restrict__ xv){
    int n = blockIdx.x, h = threadIdx.x;
    float v = xw[(size_t)n*HD+h];
    xv[(size_t)n*3*HD + h]        = v*pos[n*3+0];
    xv[(size_t)n*3*HD + HD + h]   = v*pos[n*3+1];
    xv[(size_t)n*3*HD + 2*HD + h] = v*pos[n*3+2];
}

// per-node: P = xs@pcW+pcb, squash, pv norms -> u (bf16)
__global__ __launch_bounds__(128)
void capsule_u(const float* __restrict__ xs, const float* __restrict__ xv,
               const float* __restrict__ pcW, const float* __restrict__ pcb,
               const float* __restrict__ pvW, bf16* __restrict__ u){
    __shared__ float xsS[128];
    __shared__ float Pn[128];
    __shared__ float Xv[3][128];
    __shared__ float dots[48];
    __shared__ float pvn[16];
    __shared__ float capn2[8];
    int n = blockIdx.x, t = threadIdx.x;
    xsS[t] = xs[(size_t)n*HD + t];
    Xv[0][t] = xv[(size_t)n*3*HD + t];
    Xv[1][t] = xv[(size_t)n*3*HD + HD + t];
    Xv[2][t] = xv[(size_t)n*3*HD + 2*HD + t];
    __syncthreads();
    float p = pcb[t];
    for (int k=0;k<128;++k) p += xsS[k]*pcW[(size_t)k*HD + t];
    Pn[t] = p;
    __syncthreads();
    if (t < 48){
        int pp = t/3, c = t%3;
        float a = 0.f;
        for (int hh=0; hh<128; ++hh) a += Xv[c][hh]*pvW[hh*16+pp];
        dots[t] = a;
    }
    if (t < 8){
        float a = 0.f;
        for (int d=0; d<16; ++d){ float x = Pn[t*16+d]; a += x*x; }
        capn2[t] = a;
    }
    __syncthreads();
    if (t < 16){
        float a = dots[t*3]*dots[t*3] + dots[t*3+1]*dots[t*3+1] + dots[t*3+2]*dots[t*3+2];
        pvn[t] = sqrtf(a + 1e-9f);
    }
    __syncthreads();
    int cap = t >> 4, d = t & 15;
    float n2 = capn2[cap];
    float pcv = Pn[t] * (n2/(1.f+n2)) * rsqrtf(n2 + 1e-9f);
    u[(size_t)n*HD + t] = __float2bfloat16(pcv + pvn[d]);
}

__global__ void pool_u(const int* __restrict__ gptr, const bf16* __restrict__ u,
                       float* __restrict__ U){
    int b = blockIdx.x, h = threadIdx.x;
    int s = gptr[b], e = gptr[b+1];
    s = min(max(s,0), NN); e = min(max(e,0), NN);
    float a = 0.f;
    for (int n=s; n<e; ++n) a += bf2f(u[(size_t)n*HD + h]);
    U[b*HD + h] = a;
}

// per-graph head; fp32 output
__global__ void graph_head(const float* __restrict__ U, const float* __restrict__ sW,
                           const float* __restrict__ aW, const float* __restrict__ ab,
                           const float* __restrict__ pW1, const float* __restrict__ pb1,
                           const float* __restrict__ pg1, const float* __restrict__ pbe1,
                           const float* __restrict__ pW2, const float* __restrict__ pb2,
                           const float* __restrict__ pg2, const float* __restrict__ pbe2,
                           const float* __restrict__ pW3, const float* __restrict__ pb3,
                           float* __restrict__ out){
    __shared__ float Ub[128];
    __shared__ float pooled[2048];
    __shared__ float vv[256];
    __shared__ float bbs[64], ccs[64];
    __shared__ float lg[8], aws[8];
    __shared__ float wcs[32];
    __shared__ float h1[64], h2[32];
    int b = blockIdx.x, t = threadIdx.x;
    if (t < 128) Ub[t] = U[b*HD + t];
    __syncthreads();
#pragma unroll
    for (int j=0;j<8;++j){
        int o = t + 256*j;
        int p = o >> 8, c = (o >> 5) & 7, e = o & 31;
        float a = 0.f;
#pragma unroll
        for (int d=0; d<16; ++d) a += Ub[p*16+d]*sW[((p*16+d)*8+c)*32+e];
        pooled[o] = a;
    }
    __syncthreads();
    {
        float s = 0.f;
        for (int p=0;p<8;++p) s += pooled[p*256 + t];
        s *= 0.125f;
        float n2 = s*s;
#pragma unroll
        for (int off=1; off<32; off<<=1) n2 += __shfl_xor(n2,off,32);
        vv[t] = s*(n2/(1.f+n2))*rsqrtf(n2+1e-9f);
    }
    __syncthreads();
    if (t < 64){
        int p = t>>3, c = t&7;
        float a = 0.f;
        for (int e=0;e<32;++e) a += pooled[p*256+c*32+e]*vv[c*32+e];
        bbs[t] = a;
    }
    __syncthreads();
    if (t < 64){
        int p = t>>3;
        float mx = -1e30f;
        for (int j=0;j<8;++j) mx = fmaxf(mx, bbs[p*8+j]);
        float sum = 0.f;
        for (int j=0;j<8;++j) sum += __expf(bbs[p*8+j]-mx);
        ccs[t] = __expf(bbs[t]-mx)/sum;
    }
    __syncthreads();
    {
        int c = t>>5;
        float s = 0.f;
        for (int p=0;p<8;++p) s += ccs[p*8+c]*pooled[p*256 + t];
        float n2 = s*s;
#pragma unroll
        for (int off=1; off<32; off<<=1) n2 += __shfl_xor(n2,off,32);
        vv[t] = s*(n2/(1.f+n2))*rsqrtf(n2+1e-9f);
    }
    __syncthreads();
    if (t < 8){
        float a = 0.f;
        for (int j=0;j<16;++j) a += vv[t*32+j]*aW[j];
        lg[t] = a + ab[0];
    }
    __syncthreads();
    if (t < 8){
        float mx = -1e30f;
        for (int j=0;j<8;++j) mx = fmaxf(mx, lg[j]);
        float sum = 0.f;
        for (int j=0;j<8;++j) sum += __expf(lg[j]-mx);
        aws[t] = __expf(lg[t]-mx)/sum;
    }
    __syncthreads();
    if (t < 32){
        float a = 0.f;
        for (int c=0;c<8;++c) a += aws[c]*vv[c*32+t];
        wcs[t] = a;
    }
    __syncthreads();
    if (t < 64){
        float a = 0.f;
        for (int e=0;e<32;++e) a += wcs[e]*pW1[e*64+t];
        h1[t] = silu_((a+pb1[t])*pg1[t]+pbe1[t]);
    }
    __syncthreads();
    if (t < 32){
        float a = 0.f;
        for (int j=0;j<64;++j) a += h1[j]*pW2[j*32+t];
        h2[t] = silu_((a+pb2[t])*pg2[t]+pbe2[t]);
    }
    __syncthreads();
    if (t == 0){
        float a = 0.f;
        for (int j=0;j<32;++j) a += h2[j]*pW3[j];
        a += pb3[0];
        if (!finite_(a)) a = 999.f;
        out[b] = a;
    }
}

__global__ void sentinel_k(float* __restrict__ out, float v){
    out[threadIdx.x] = v;
}

// ---------------- host side ----------------
extern "C" void kernel_launch(void* const* d_in, const int* in_sizes, int n_in,
                              void* d_out, int out_size, void* d_ws, size_t ws_size,
                              hipStream_t stream)
{
    (void)in_sizes; (void)n_in; (void)out_size;
    const float* x    = (const float*)d_in[0];
    const float* eat  = (const float*)d_in[1];
    const float* pos  = (const float*)d_in[2];
    const int*  eidx  = (const int*)d_in[3];
    const int*  batch = (const int*)d_in[4];
    const float* neW1=(const float*)d_in[5],  *neb1=(const float*)d_in[6],
               * neg1=(const float*)d_in[7],  *nebe1=(const float*)d_in[8];
    const float* neW2=(const float*)d_in[9],  *neb2=(const float*)d_in[10],
               * neg2=(const float*)d_in[11], *nebe2=(const float*)d_in[12];
    const float* eeW1=(const float*)d_in[13], *eeb1=(const float*)d_in[14];
    const float* eeW2=(const float*)d_in[15], *eeb2=(const float*)d_in[16];
    const float* ivW =(const float*)d_in[17], *ivb =(const float*)d_in[18];
    const float* cWma=(const float*)d_in[19], *cWmb=(const float*)d_in[20],
               * cWme=(const float*)d_in[21], *cbm =(const float*)d_in[22];
    const float* cWsx=(const float*)d_in[23], *cWsa=(const float*)d_in[24],
               * cbs =(const float*)d_in[25];
    const float* cWv1=(const float*)d_in[26], *cbv1=(const float*)d_in[27],
               * cWv2=(const float*)d_in[28], *cbv2=(const float*)d_in[29];
    const float* lng =(const float*)d_in[30], *lnb =(const float*)d_in[31],
               * vsg =(const float*)d_in[32];
    const float* pcW =(const float*)d_in[33], *pcb =(const float*)d_in[34];
    const float* pvW =(const float*)d_in[35];
    const float* sW  =(const float*)d_in[36];
    const float* aW  =(const float*)d_in[37], *ab  =(const float*)d_in[38];
    const float* pW1 =(const float*)d_in[39], *pb1 =(const float*)d_in[40],
               * pg1 =(const float*)d_in[41], *pbe1=(const float*)d_in[42];
    const float* pW2 =(const float*)d_in[43], *pb2 =(const float*)d_in[44],
               * pg2 =(const float*)d_in[45], *pbe2=(const float*)d_in[46];
    const float* pW3 =(const float*)d_in[47], *pb3 =(const float*)d_in[48];

    const int* src = eidx;
    const int* dst = eidx + NE;

    char* wp = (char*)d_ws;
    auto alloc = [&](size_t bytes)->char*{
        char* p = wp;
        wp += (bytes + 255) & ~(size_t)255;
        return p;
    };
    bf16*  bufM  = (bf16*) alloc((size_t)ECM*HD*2);       // 13.63 MB
    bf16*  bufG  = (bf16*) alloc((size_t)ECM*HD*2);       // 13.63 MB
    float* xs    = (float*)alloc((size_t)NN*HD*4);        // 25.6 MB
    float* xvA   = (float*)alloc((size_t)NN*3*HD*4);      // 76.8 MB
    float* xvB   = (float*)alloc((size_t)NN*3*HD*4);      // 76.8 MB
    bf16*  An    = (bf16*) alloc((size_t)NN*HD*2);        // 12.8 MB
    bf16*  Bn    = (bf16*) alloc((size_t)NN*HD*2);        // 12.8 MB
    float* Ubuf  = (float*)alloc((size_t)NB*HD*4);
    int* rowptr  = (int*)alloc((size_t)(NN+1)*4);
    int* cnt     = (int*)alloc((size_t)NN*4);
    int* elist   = (int*)alloc((size_t)NE*4);
    int* srcp    = (int*)alloc((size_t)NE*4);
    int* dstp    = (int*)alloc((size_t)NE*4);
    int* gptr    = (int*)alloc((size_t)(NB+1)*4);
    size_t used  = (size_t)(wp - (char*)d_ws);            // ~240 MB

    if (used > ws_size){
        sentinel_k<<<1, NB, 0, stream>>>((float*)d_out, -1.f - (float)(ws_size >> 20));
        return;
    }
    float* tmpF = xvB;          // embeddings scratch (xvB dead until layer 0 update)
    bf16*  ubuf = An;           // capsule u (An dead after layers)

    // ---- CSR + gptr ----
    hipMemsetAsync(cnt, 0, (size_t)NN*4, stream);
    hist_kernel<<<(NE+255)/256, 256, 0, stream>>>(dst, cnt, NE, NN);
    scan_kernel<<<1, 256, 0, stream>>>(cnt, rowptr, NN);
    hipMemsetAsync(cnt, 0, (size_t)NN*4, stream);
    fill_kernel<<<(NE+255)/256, 256, 0, stream>>>(src, dst, rowptr, cnt, elist, srcp, dstp, NE);
    gptr_kernel<<<(NN+255)/256, 256, 0, stream>>>(batch, gptr);

    const int GN = (NN+63)/64;
    const int GE = ECM/64;
    const int GS = (CN+NPB-1)/NPB;

    // ---- node embeddings ----
    gemmk<M_BNSILU><<<GN,256,0,stream>>>(x, neW1, neb1, neg1, nebe1, tmpF, 0, NN, 92);
    gemmk<M_BNSILU><<<GN,256,0,stream>>>(tmpF, neW2, neb2, neg2, nebe2, xs, 0, NN, 128);
    gemmk<M_BIAS><<<GN,256,0,stream>>>(xs, ivW, ivb, nullptr, nullptr, tmpF, 0, NN, 128);
    xv_init<<<NN, 128, 0, stream>>>(tmpF, pos, xvA);

    // ---- message-passing layers ----
    float* xvO = xvA;
    float* xvN = xvB;
    for (int l=0; l<3; ++l){
        const float* Wma = cWma + (size_t)l*HD*HD;
        const float* Wmb = cWmb + (size_t)l*HD*HD;
        const float* Wme = cWme + (size_t)l*HD*HD;
        const float* bm  = cbm  + (size_t)l*HD;
        const float* Wsx = cWsx + (size_t)l*HD*HD;
        const float* Wsa = cWsa + (size_t)l*HD*HD;
        const float* bs  = cbs  + (size_t)l*HD;
        const float* Wv1 = cWv1 + (size_t)l*HD*HD;
        const float* bv1 = cbv1 + (size_t)l*HD;
        const float* Wv2 = cWv2 + (size_t)l*HD*HD;
        const float* bv2 = cbv2 + (size_t)l*HD;

        gemmk<M_PLAIN><<<GN,256,0,stream>>>(xs, Wma, nullptr, nullptr, nullptr, An, 1, NN, 128);
        gemmk<M_PLAIN><<<GN,256,0,stream>>>(xs, Wmb, nullptr, nullptr, nullptr, Bn, 1, NN, 128);

        for (int c=0; c<NCH; ++c){
            int n0 = c*CN, n1 = n0+CN;
            edge_pipe<<<GE,256,0,stream>>>(eat, elist, srcp, dstp,
                                           eeW1, eeb1, eeW2, eeb2, Wme, bm,
                                           An, Bn, Wv1, bv1,
                                           rowptr, n0, n1, bufM, bufG);
            su_fused<<<GS,128,0,stream>>>(rowptr, srcp, pos, bufM, bufG,
                                          xvO, xvN, xs,
                                          Wv2, bv2, Wsx, Wsa, bs,
                                          lng + (size_t)l*HD, lnb + (size_t)l*HD,
                                          vsg + (size_t)l*HD, l>0 ? 1 : 0, n0, n1);
        }
        float* t = xvO; xvO = xvN; xvN = t;
    }

    // ---- capsules & head ----
    capsule_u<<<NN, 128, 0, stream>>>(xs, xvO, pcW, pcb, pvW, ubuf);
    pool_u<<<NB, 128, 0, stream>>>(gptr, ubuf, Ubuf);
    graph_head<<<NB, 256, 0, stream>>>(Ubuf, sW, aW, ab,
                                       pW1, pb1, pg1, pbe1,
                                       pW2, pb2, pg2, pbe2,
                                       pW3, pb3, (float*)d_out);
}

// Round 11
// 5758.085 us; speedup vs baseline: 1.9130x; 1.4362x over previous
//
#include <hip/hip_runtime.h>
#include <hip/hip_bf16.h>
#include <math.h>

#define NN 50000
#define NE 400000
#define HD 128
#define NB 64
#define NCH 8
#define CN 6250          // nodes per chunk
#define ECM 53248        // max edges per chunk (mean 50000, sigma~209; +15.5 sigma)
#define NPB 8            // nodes per block in su_fused

typedef __hip_bfloat16 bf16;
typedef __attribute__((ext_vector_type(4))) unsigned short us4;
typedef __attribute__((ext_vector_type(8))) short s8v;    // 8 bf16 (4 VGPRs) MFMA frag
typedef __attribute__((ext_vector_type(4))) float f4v;    // MFMA accumulator

__device__ __forceinline__ float sigm_(float x){ return 1.f/(1.f+__expf(-x)); }
__device__ __forceinline__ float silu_(float x){ return x*sigm_(x); }
__device__ __forceinline__ float bf2f(bf16 x){ return __bfloat162float(x); }
__device__ __forceinline__ float bu2f(unsigned short u){ return __uint_as_float(((unsigned)u)<<16); }
__device__ __forceinline__ unsigned short f2bu(float f){
    bf16 h = __float2bfloat16(f);
    return *reinterpret_cast<unsigned short*>(&h);
}
__device__ __forceinline__ bool finite_(float v){ return fabsf(v) <= 1e37f; }

enum { M_PLAIN=0, M_BIAS, M_BNSILU };

// ---------------- split-transpose weight prep: W[k][n] -> H/L[n][k] (bf16 hi/lo) ----
__global__ void wprep(const float* __restrict__ W, bf16* __restrict__ H, bf16* __restrict__ L){
    int i = blockIdx.x*256 + threadIdx.x;       // 16384 elements
    int k = i >> 7, n = i & 127;
    float w = W[i];
    bf16 h = __float2bfloat16(w);
    float r = w - bf2f(h);
    H[n*128 + k] = h;
    L[n*128 + k] = __float2bfloat16(r);
}

// ---------------- generic tiled GEMM: C[M,128] = epilogue(A[M,K] @ W[K,128]) ----------
template<int MODE>
__global__ __launch_bounds__(256)
void gemmk(const float* __restrict__ A, const float* __restrict__ W,
           const float* __restrict__ bias, const float* __restrict__ gg,
           const float* __restrict__ be, void* __restrict__ Cv, int owf, int M, int K)
{
    const int row0 = blockIdx.x * 64;
    if (row0 >= M) return;
    __shared__ float As[32][68];
    __shared__ float Ws[32][128];
    const int tid = threadIdx.x;
    const int tx = tid & 15, ty = tid >> 4;
    const int col0 = tx*8;
    float acc[4][8];
#pragma unroll
    for (int r=0;r<4;++r)
#pragma unroll
        for (int j=0;j<8;++j) acc[r][j]=0.f;
    const int mload = tid >> 2;
    const int kload = (tid & 3) << 3;
    const int grow = row0 + mload;
    const bool rv = grow < M;

    for (int k0 = 0; k0 < K; k0 += 32) {
        if (rv && ((K & 3) == 0) && (k0 + kload + 8 <= K)) {
            const float* ap = A + (size_t)grow*K + k0 + kload;
            float4 v0 = *(const float4*)ap;
            float4 v1 = *(const float4*)(ap+4);
            As[kload+0][mload]=v0.x; As[kload+1][mload]=v0.y;
            As[kload+2][mload]=v0.z; As[kload+3][mload]=v0.w;
            As[kload+4][mload]=v1.x; As[kload+5][mload]=v1.y;
            As[kload+6][mload]=v1.z; As[kload+7][mload]=v1.w;
        } else {
#pragma unroll
            for (int j=0;j<8;++j){
                int kg = k0 + kload + j;
                As[kload+j][mload] = (rv && kg<K) ? A[(size_t)grow*K+kg] : 0.f;
            }
        }
        if (k0 + 32 <= K) {
#pragma unroll
            for (int j=0;j<4;++j){
                int el = (tid + j*256)*4;
                int kk = el >> 7, col = el & 127;
                *(float4*)&Ws[kk][col] = *(const float4*)&W[(size_t)(k0+kk)*HD + col];
            }
        } else {
#pragma unroll
            for (int j=0;j<16;++j){
                int el = tid*16 + j;
                int kk = el >> 7, col = el & 127;
                int kg = k0 + kk;
                Ws[kk][col] = (kg < K) ? W[(size_t)kg*HD + col] : 0.f;
            }
        }
        __syncthreads();
#pragma unroll
        for (int k=0;k<32;++k){
            float4 a4 = *(const float4*)&As[k][ty*4];
            float4 w0 = *(const float4*)&Ws[k][col0];
            float4 w1 = *(const float4*)&Ws[k][col0+4];
            float av[4] = {a4.x,a4.y,a4.z,a4.w};
            float wv[8] = {w0.x,w0.y,w0.z,w0.w,w1.x,w1.y,w1.z,w1.w};
#pragma unroll
            for (int r=0;r<4;++r)
#pragma unroll
                for (int j=0;j<8;++j) acc[r][j] += av[r]*wv[j];
        }
        __syncthreads();
    }
#pragma unroll
    for (int r=0;r<4;++r){
        int orow = row0 + ty*4 + r;
        if (orow >= M) continue;
        float o[8];
#pragma unroll
        for (int j=0;j<8;++j) o[j]=acc[r][j];
        if constexpr (MODE==M_BIAS || MODE==M_BNSILU){
#pragma unroll
            for (int j=0;j<8;++j) o[j] += bias[col0+j];
        }
        if constexpr (MODE==M_BNSILU){
#pragma unroll
            for (int j=0;j<8;++j) o[j] = silu_(o[j]*gg[col0+j] + be[col0+j]);
        }
        if (owf){
            bf16* C = (bf16*)Cv;
#pragma unroll
            for (int j=0;j<8;++j) C[(size_t)orow*HD+col0+j] = __float2bfloat16(o[j]);
        } else {
            float* C = (float*)Cv;
            float4* cp = (float4*)&C[(size_t)orow*HD + col0];
            cp[0] = make_float4(o[0],o[1],o[2],o[3]);
            cp[1] = make_float4(o[4],o[5],o[6],o[7]);
        }
    }
}

// ---------------- MFMA fused edge pipeline for one chunk ----------------
// 64 edges/block, 4 waves column-partitioned (32 cols each).
// G1 (K=41) fp32 VALU -> T1 bf16; ph0/1/2 (K=128) split-bf16 MFMA.
__global__ __launch_bounds__(256)
void edge_pipe(const float* __restrict__ eat,
               const int* __restrict__ elist, const int* __restrict__ srcp,
               const int* __restrict__ dstp,
               const float* __restrict__ W1, const float* __restrict__ b1,
               const bf16* __restrict__ W2h, const bf16* __restrict__ W2l,
               const float* __restrict__ b2,
               const bf16* __restrict__ Wmeh, const bf16* __restrict__ Wmel,
               const float* __restrict__ bm,
               const bf16* __restrict__ An, const bf16* __restrict__ Bn,
               const bf16* __restrict__ Wv1h, const bf16* __restrict__ Wv1l,
               const float* __restrict__ bv1,
               const int* __restrict__ rp, int rn0, int rn1,
               bf16* __restrict__ outM, bf16* __restrict__ outG)
{
    __shared__ __align__(16) unsigned short T1[64][136];
    __shared__ __align__(16) unsigned short T2[64][136];
    __shared__ float Ws[32][128];
    __shared__ int seS[64], deS[64];

    const int cbase = rp[rn0];
    const int Ml = min(ECM, max(rp[rn1]-cbase, 0));
    const int row0 = blockIdx.x*64;
    if (row0 >= Ml) return;
    const int tid = threadIdx.x;
    const int lane = tid & 63, wave = tid >> 6;
    const int quad = lane >> 4, n16 = lane & 15;

    if (tid < 64){
        int r = row0 + tid;
        bool v = r < Ml;
        int p = cbase + (v ? r : 0);
        seS[tid] = v ? srcp[p] : 0;
        deS[tid] = v ? dstp[p] : 0;
    }

    // ---------- G1: e1 = silu(eat[elist] @ W1 + b1), K=41, fp32 ----------
    {
        float (*As)[68] = reinterpret_cast<float(*)[68]>(T2);
        const int tx = tid & 15, ty = tid >> 4, col0 = tx*8;
        const int mload = tid >> 2, kload = (tid & 3) << 3;
        const int grow = row0 + mload;
        const bool rv = grow < Ml;
        int arow = 0;
        if (rv){ int e = elist[cbase+grow]; arow = min(max(e,0), NE-1); }
        float acc[4][8];
#pragma unroll
        for (int r=0;r<4;++r)
#pragma unroll
            for (int j=0;j<8;++j) acc[r][j]=0.f;
        for (int k0=0;k0<41;k0+=32){
#pragma unroll
            for (int j=0;j<8;++j){
                int kg=k0+kload+j;
                As[kload+j][mload] = (rv&&kg<41)? eat[(size_t)arow*41+kg] : 0.f;
            }
#pragma unroll
            for (int j=0;j<16;++j){
                int el=tid*16+j;
                int kk=el>>7, col=el&127;
                int kg=k0+kk;
                Ws[kk][col] = (kg<41)? W1[(size_t)kg*HD+col] : 0.f;
            }
            __syncthreads();
#pragma unroll
            for (int k=0;k<32;++k){
                float4 a4=*(const float4*)&As[k][ty*4];
                float4 w0=*(const float4*)&Ws[k][col0];
                float4 w1=*(const float4*)&Ws[k][col0+4];
                float av[4]={a4.x,a4.y,a4.z,a4.w};
                float wv[8]={w0.x,w0.y,w0.z,w0.w,w1.x,w1.y,w1.z,w1.w};
#pragma unroll
                for (int r=0;r<4;++r)
#pragma unroll
                    for (int j=0;j<8;++j) acc[r][j]+=av[r]*wv[j];
            }
            __syncthreads();
        }
#pragma unroll
        for (int r=0;r<4;++r){
            unsigned short* dp = &T1[ty*4+r][col0];
#pragma unroll
            for (int j=0;j<8;++j) dp[j] = f2bu(silu_(acc[r][j]+b1[col0+j]));
        }
    }
    __syncthreads();

    // ---------- MFMA phases (K=128, split-bf16 weights) ----------
    const int cwb = wave*32;
    f4v acc[4][2];
    s8v Bh[2][4], Bl[2][4];

    for (int ph=0; ph<3; ++ph){
        const bf16* WH = (ph==0)? W2h : (ph==1)? Wmeh : Wv1h;
        const bf16* WL = (ph==0)? W2l : (ph==1)? Wmel : Wv1l;
        const unsigned short (*Tin)[136] = (ph==1)? (const unsigned short(*)[136])T2
                                                  : (const unsigned short(*)[136])T1;
        // B fragments resident (per-wave unique cols, no duplication)
#pragma unroll
        for (int ct=0; ct<2; ++ct){
            int nn = cwb + ct*16 + n16;
            const s8v* hp = (const s8v*)&WH[(size_t)nn*128];
            const s8v* lp = (const s8v*)&WL[(size_t)nn*128];
#pragma unroll
            for (int kc=0; kc<4; ++kc){
                Bh[ct][kc] = hp[kc*4 + quad];
                Bl[ct][kc] = lp[kc*4 + quad];
            }
        }
#pragma unroll
        for (int rt=0;rt<4;++rt)
#pragma unroll
            for (int ct=0;ct<2;++ct) acc[rt][ct] = (f4v){0.f,0.f,0.f,0.f};

#pragma unroll
        for (int kc=0; kc<4; ++kc){
#pragma unroll
            for (int rt=0; rt<4; ++rt){
                s8v a = *(const s8v*)&Tin[rt*16 + n16][kc*32 + quad*8];
#pragma unroll
                for (int ct=0; ct<2; ++ct){
                    acc[rt][ct] = __builtin_amdgcn_mfma_f32_16x16x32_bf16(a, Bh[ct][kc], acc[rt][ct], 0,0,0);
                    acc[rt][ct] = __builtin_amdgcn_mfma_f32_16x16x32_bf16(a, Bl[ct][kc], acc[rt][ct], 0,0,0);
                }
            }
        }
        // epilogue (C-layout: col=lane&15 -> n16, row=quad*4+reg)
        if (ph==0){
#pragma unroll
            for (int ct=0; ct<2; ++ct){
                int col = cwb + ct*16 + n16;
                float bc = b2[col];
#pragma unroll
                for (int rt=0; rt<4; ++rt)
#pragma unroll
                    for (int i=0;i<4;++i)
                        T2[rt*16 + quad*4 + i][col] = f2bu(silu_(acc[rt][ct][i] + bc));
            }
            __syncthreads();
        } else if (ph==1){
#pragma unroll
            for (int ct=0; ct<2; ++ct){
                int col = cwb + ct*16 + n16;
                float bc = bm[col];
#pragma unroll
                for (int rt=0; rt<4; ++rt)
#pragma unroll
                    for (int i=0;i<4;++i){
                        int row = rt*16 + quad*4 + i;
                        int se = seS[row], de = deS[row];
                        float v = silu_(acc[rt][ct][i] + bc
                                        + bf2f(An[(size_t)se*HD+col])
                                        + bf2f(Bn[(size_t)de*HD+col]));
                        T1[row][col] = f2bu(v);
                    }
            }
            __syncthreads();
            {   // coalesced copy T1 -> outM
                int row = tid >> 2, seg = tid & 3;
                if (row0 + row < Ml){
                    const s8v* s = (const s8v*)&T1[row][seg*32];
                    s8v* d = (s8v*)&outM[(size_t)(row0+row)*HD + seg*32];
                    d[0]=s[0]; d[1]=s[1]; d[2]=s[2]; d[3]=s[3];
                }
            }
        } else {
#pragma unroll
            for (int ct=0; ct<2; ++ct){
                int col = cwb + ct*16 + n16;
                float bc = bv1[col];
#pragma unroll
                for (int rt=0; rt<4; ++rt)
#pragma unroll
                    for (int i=0;i<4;++i)
                        T2[rt*16 + quad*4 + i][col] = f2bu(acc[rt][ct][i] + bc);
            }
            __syncthreads();
            {   // coalesced copy T2 -> outG
                int row = tid >> 2, seg = tid & 3;
                if (row0 + row < Ml){
                    const s8v* s = (const s8v*)&T2[row][seg*32];
                    s8v* d = (s8v*)&outG[(size_t)(row0+row)*HD + seg*32];
                    d[0]=s[0]; d[1]=s[1]; d[2]=s[2]; d[3]=s[3];
                }
            }
        }
    }
}

// ---------------- fused scatter + GEMVs + layernorm/update ----------------
__global__ __launch_bounds__(128)
void su_fused(const int* __restrict__ rp, const int* __restrict__ srcp,
              const float* __restrict__ pos,
              const bf16* __restrict__ mB, const bf16* __restrict__ gB,
              const float* __restrict__ xvO, float* __restrict__ xvN,
              float* __restrict__ xs,
              const float* __restrict__ Wv2, const float* __restrict__ bv2,
              const float* __restrict__ Wsx, const float* __restrict__ Wsa,
              const float* __restrict__ bs,
              const float* __restrict__ lng, const float* __restrict__ lnb,
              const float* __restrict__ vsg, int addRes, int n0, int n1)
{
    __shared__ float mdS[NPB][3][128];
    __shared__ float smS[NPB][128];
    __shared__ float xsS[NPB][128];
    __shared__ float red[4];
    __shared__ float red2[2];
    const int h = threadIdx.x;
    const int base = n0 + blockIdx.x*NPB;
    const int cbase = rp[n0];
    float av0[NPB],av1[NPB],av2[NPB],sd0[NPB],sd1[NPB],sd2[NPB];
#pragma unroll
    for (int i=0;i<NPB;++i){
        int n = base+i;
        bool valid = n < n1;
        float sm=0,a0=0,a1=0,a2=0,m0=0,m1=0,m2=0,d0s=0,d1s=0,d2s=0;
        if (valid){
            int p0=rp[n], p1=rp[n+1];
            float px0=pos[n*3],px1=pos[n*3+1],px2=pos[n*3+2];
            for (int p=p0;p<p1;++p){
                int ii=p-cbase; if ((unsigned)ii>=(unsigned)ECM) break;
                float mh=bf2f(mB[(size_t)ii*HD+h]);
                float gh=bf2f(gB[(size_t)ii*HD+h]);
                int sn=srcp[p]; sn=min(max(sn,0),NN-1);
                float d0=px0-pos[sn*3], d1=px1-pos[sn*3+1], d2=px2-pos[sn*3+2];
                sm+=mh;
                a0+=xvO[(size_t)sn*3*HD+h]*gh;
                a1+=xvO[(size_t)sn*3*HD+HD+h]*gh;
                a2+=xvO[(size_t)sn*3*HD+2*HD+h]*gh;
                m0+=mh*d0; m1+=mh*d1; m2+=mh*d2;
                d0s+=d0; d1s+=d1; d2s+=d2;
            }
        }
        mdS[i][0][h]=m0; mdS[i][1][h]=m1; mdS[i][2][h]=m2;
        smS[i][h]=sm;
        xsS[i][h]= valid ? xs[(size_t)n*HD+h] : 0.f;
        av0[i]=a0; av1[i]=a1; av2[i]=a2; sd0[i]=d0s; sd1[i]=d1s; sd2[i]=d2s;
    }
    __syncthreads();
    float g0[NPB],g1v[NPB],g2[NPB],xw[NPB],sw[NPB];
#pragma unroll
    for (int i=0;i<NPB;++i){ g0[i]=0;g1v[i]=0;g2[i]=0;xw[i]=0;sw[i]=0; }
    for (int k=0;k<HD;++k){
        float w2=Wv2[k*HD+h], wx=Wsx[k*HD+h], wa=Wsa[k*HD+h];
#pragma unroll
        for (int i=0;i<NPB;++i){
            g0[i]+=mdS[i][0][k]*w2;
            g1v[i]+=mdS[i][1][k]*w2;
            g2[i]+=mdS[i][2][k]*w2;
            xw[i]+=xsS[i][k]*wx;
            sw[i]+=smS[i][k]*wa;
        }
    }
    const float b2v=bv2[h], bsv=bs[h], lgv=lng[h], lbv=lnb[h], vgv=vsg[h];
    const int w = h >> 6;
    for (int i=0;i<NPB;++i){
        int n = base+i;
        bool valid = n < n1;
        float xc = xw[i]+sw[i]+bsv;
        float s1=xc, s2=xc*xc;
#pragma unroll
        for (int off=1; off<64; off<<=1){ s1+=__shfl_xor(s1,off,64); s2+=__shfl_xor(s2,off,64); }
        if ((h&63)==0){ red[w*2]=s1; red[w*2+1]=s2; }
        __syncthreads();
        s1=red[0]+red[2]; s2=red[1]+red[3];
        float mu=s1*(1.f/128.f);
        float var=fmaxf(s2*(1.f/128.f)-mu*mu, 0.f);
        float xn=(xc-mu)*rsqrtf(var+1e-5f)*lgv+lbv;
        float ov0=0,ov1=0,ov2=0;
        if (valid){
            ov0=xvO[(size_t)n*3*HD+h];
            ov1=xvO[(size_t)n*3*HD+HD+h];
            ov2=xvO[(size_t)n*3*HD+2*HD+h];
        }
        float v0=ov0+av0[i]+g0[i]+b2v*sd0[i];
        float v1=ov1+av1[i]+g1v[i]+b2v*sd1[i];
        float v2=ov2+av2[i]+g2[i]+b2v*sd2[i];
        float q=v0*v0+v1*v1+v2*v2;
#pragma unroll
        for (int off=1; off<64; off<<=1) q+=__shfl_xor(q,off,64);
        if ((h&63)==0) red2[w]=q;
        __syncthreads();
        q=fmaxf(red2[0]+red2[1], 0.f);
        float nrm=sqrtf(q*(1.f/128.f)+1e-5f);
        float scale=vgv*sigm_(xn)/nrm;
        float r0=v0*scale, r1=v1*scale, r2=v2*scale;
        float nxs=silu_(xn);
        if (addRes){ nxs+=xsS[i][h]; r0+=ov0; r1+=ov1; r2+=ov2; }
        if (valid){
            xs[(size_t)n*HD+h]=nxs;
            xvN[(size_t)n*3*HD+h]=r0;
            xvN[(size_t)n*3*HD+HD+h]=r1;
            xvN[(size_t)n*3*HD+2*HD+h]=r2;
        }
        __syncthreads();
    }
}

// ---------------- CSR build ----------------
__global__ void hist_kernel(const int* __restrict__ idx, int* __restrict__ cnt, int n, int nb){
    int i = blockIdx.x*256 + threadIdx.x;
    if (i < n){
        int v = idx[i]; v = min(max(v,0), nb-1);
        atomicAdd(&cnt[v], 1);
    }
}

__global__ void scan_kernel(const int* __restrict__ cnt, int* __restrict__ out, int n){
    __shared__ int sums[256];
    int t = threadIdx.x;
    int chunk = (n + 255) / 256;
    int lo = t*chunk, hi = lo+chunk; if (hi > n) hi = n; if (lo > n) lo = n;
    int s = 0;
    for (int i=lo;i<hi;++i) s += cnt[i];
    sums[t] = s;
    __syncthreads();
    if (t==0){ int run=0; for (int i=0;i<256;++i){ int v=sums[i]; sums[i]=run; run+=v; } }
    __syncthreads();
    int run = sums[t];
    for (int i=lo;i<hi;++i){ out[i]=run; run+=cnt[i]; }
    if (hi == n) out[n] = run;
}

__global__ void fill_kernel(const int* __restrict__ src, const int* __restrict__ dst,
                            const int* __restrict__ rowptr, int* __restrict__ cur,
                            int* __restrict__ elist, int* __restrict__ srcp,
                            int* __restrict__ dstp, int n){
    int e = blockIdx.x*256 + threadIdx.x;
    if (e < n){
        int d = dst[e]; d = min(max(d,0), NN-1);
        int slot = atomicAdd(&cur[d], 1);
        int p = rowptr[d] + slot;
        if (p >= 0 && p < NE){
            elist[p] = e;
            int s = src[e];
            srcp[p] = min(max(s,0), NN-1);
            dstp[p] = d;
        }
    }
}

__global__ void gptr_kernel(const int* __restrict__ batch, int* __restrict__ gptr){
    int n = blockIdx.x*256 + threadIdx.x;
    if (n >= NN) return;
    int b = batch[n]; b = min(max(b,0), NB-1);
    if (n == 0){
        for (int g=0; g<=b; ++g) gptr[g] = 0;
    } else {
        int bp = batch[n-1]; bp = min(max(bp,0), NB-1);
        for (int g=bp+1; g<=b; ++g) gptr[g] = n;
    }
    if (n == NN-1){
        for (int g=b+1; g<=NB; ++g) gptr[g] = NN;
    }
}

__global__ void xv_init(const float* __restrict__ xw, const float* __restrict__ pos,
                        float* __restrict__ xv){
    int n = blockIdx.x, h = threadIdx.x;
    float v = xw[(size_t)n*HD+h];
    xv[(size_t)n*3*HD + h]        = v*pos[n*3+0];
    xv[(size_t)n*3*HD + HD + h]   = v*pos[n*3+1];
    xv[(size_t)n*3*HD + 2*HD + h] = v*pos[n*3+2];
}

__global__ __launch_bounds__(128)
void capsule_u(const float* __restrict__ xs, const float* __restrict__ xv,
               const float* __restrict__ pcW, const float* __restrict__ pcb,
               const float* __restrict__ pvW, bf16* __restrict__ u){
    __shared__ float xsS[128];
    __shared__ float Pn[128];
    __shared__ float Xv[3][128];
    __shared__ float dots[48];
    __shared__ float pvn[16];
    __shared__ float capn2[8];
    int n = blockIdx.x, t = threadIdx.x;
    xsS[t] = xs[(size_t)n*HD + t];
    Xv[0][t] = xv[(size_t)n*3*HD + t];
    Xv[1][t] = xv[(size_t)n*3*HD + HD + t];
    Xv[2][t] = xv[(size_t)n*3*HD + 2*HD + t];
    __syncthreads();
    float p = pcb[t];
    for (int k=0;k<128;++k) p += xsS[k]*pcW[(size_t)k*HD + t];
    Pn[t] = p;
    __syncthreads();
    if (t < 48){
        int pp = t/3, c = t%3;
        float a = 0.f;
        for (int hh=0; hh<128; ++hh) a += Xv[c][hh]*pvW[hh*16+pp];
        dots[t] = a;
    }
    if (t < 8){
        float a = 0.f;
        for (int d=0; d<16; ++d){ float x = Pn[t*16+d]; a += x*x; }
        capn2[t] = a;
    }
    __syncthreads();
    if (t < 16){
        float a = dots[t*3]*dots[t*3] + dots[t*3+1]*dots[t*3+1] + dots[t*3+2]*dots[t*3+2];
        pvn[t] = sqrtf(a + 1e-9f);
    }
    __syncthreads();
    int cap = t >> 4, d = t & 15;
    float n2 = capn2[cap];
    float pcv = Pn[t] * (n2/(1.f+n2)) * rsqrtf(n2 + 1e-9f);
    u[(size_t)n*HD + t] = __float2bfloat16(pcv + pvn[d]);
}

__global__ void pool_u(const int* __restrict__ gptr, const bf16* __restrict__ u,
                       float* __restrict__ U){
    int b = blockIdx.x, h = threadIdx.x;
    int s = gptr[b], e = gptr[b+1];
    s = min(max(s,0), NN); e = min(max(e,0), NN);
    float a = 0.f;
    for (int n=s; n<e; ++n) a += bf2f(u[(size_t)n*HD + h]);
    U[b*HD + h] = a;
}

__global__ void graph_head(const float* __restrict__ U, const float* __restrict__ sW,
                           const float* __restrict__ aW, const float* __restrict__ ab,
                           const float* __restrict__ pW1, const float* __restrict__ pb1,
                           const float* __restrict__ pg1, const float* __restrict__ pbe1,
                           const float* __restrict__ pW2, const float* __restrict__ pb2,
                           const float* __restrict__ pg2, const float* __restrict__ pbe2,
                           const float* __restrict__ pW3, const float* __restrict__ pb3,
                           float* __restrict__ out){
    __shared__ float Ub[128];
    __shared__ float pooled[2048];
    __shared__ float vv[256];
    __shared__ float bbs[64], ccs[64];
    __shared__ float lg[8], aws[8];
    __shared__ float wcs[32];
    __shared__ float h1[64], h2[32];
    int b = blockIdx.x, t = threadIdx.x;
    if (t < 128) Ub[t] = U[b*HD + t];
    __syncthreads();
#pragma unroll
    for (int j=0;j<8;++j){
        int o = t + 256*j;
        int p = o >> 8, c = (o >> 5) & 7, e = o & 31;
        float a = 0.f;
#pragma unroll
        for (int d=0; d<16; ++d) a += Ub[p*16+d]*sW[((p*16+d)*8+c)*32+e];
        pooled[o] = a;
    }
    __syncthreads();
    {
        float s = 0.f;
        for (int p=0;p<8;++p) s += pooled[p*256 + t];
        s *= 0.125f;
        float n2 = s*s;
#pragma unroll
        for (int off=1; off<32; off<<=1) n2 += __shfl_xor(n2,off,32);
        vv[t] = s*(n2/(1.f+n2))*rsqrtf(n2+1e-9f);
    }
    __syncthreads();
    if (t < 64){
        int p = t>>3, c = t&7;
        float a = 0.f;
        for (int e=0;e<32;++e) a += pooled[p*256+c*32+e]*vv[c*32+e];
        bbs[t] = a;
    }
    __syncthreads();
    if (t < 64){
        int p = t>>3;
        float mx = -1e30f;
        for (int j=0;j<8;++j) mx = fmaxf(mx, bbs[p*8+j]);
        float sum = 0.f;
        for (int j=0;j<8;++j) sum += __expf(bbs[p*8+j]-mx);
        ccs[t] = __expf(bbs[t]-mx)/sum;
    }
    __syncthreads();
    {
        int c = t>>5;
        float s = 0.f;
        for (int p=0;p<8;++p) s += ccs[p*8+c]*pooled[p*256 + t];
        float n2 = s*s;
#pragma unroll
        for (int off=1; off<32; off<<=1) n2 += __shfl_xor(n2,off,32);
        vv[t] = s*(n2/(1.f+n2))*rsqrtf(n2+1e-9f);
    }
    __syncthreads();
    if (t < 8){
        float a = 0.f;
        for (int j=0;j<16;++j) a += vv[t*32+j]*aW[j];
        lg[t] = a + ab[0];
    }
    __syncthreads();
    if (t < 8){
        float mx = -1e30f;
        for (int j=0;j<8;++j) mx = fmaxf(mx, lg[j]);
        float sum = 0.f;
        for (int j=0;j<8;++j) sum += __expf(lg[j]-mx);
        aws[t] = __expf(lg[t]-mx)/sum;
    }
    __syncthreads();
    if (t < 32){
        float a = 0.f;
        for (int c=0;c<8;++c) a += aws[c]*vv[c*32+t];
        wcs[t] = a;
    }
    __syncthreads();
    if (t < 64){
        float a = 0.f;
        for (int e=0;e<32;++e) a += wcs[e]*pW1[e*64+t];
        h1[t] = silu_((a+pb1[t])*pg1[t]+pbe1[t]);
    }
    __syncthreads();
    if (t < 32){
        float a = 0.f;
        for (int j=0;j<64;++j) a += h1[j]*pW2[j*32+t];
        h2[t] = silu_((a+pb2[t])*pg2[t]+pbe2[t]);
    }
    __syncthreads();
    if (t == 0){
        float a = 0.f;
        for (int j=0;j<32;++j) a += h2[j]*pW3[j];
        a += pb3[0];
        if (!finite_(a)) a = 999.f;
        out[b] = a;
    }
}

__global__ void sentinel_k(float* __restrict__ out, float v){
    out[threadIdx.x] = v;
}

// ---------------- host side ----------------
extern "C" void kernel_launch(void* const* d_in, const int* in_sizes, int n_in,
                              void* d_out, int out_size, void* d_ws, size_t ws_size,
                              hipStream_t stream)
{
    (void)in_sizes; (void)n_in; (void)out_size;
    const float* x    = (const float*)d_in[0];
    const float* eat  = (const float*)d_in[1];
    const float* pos  = (const float*)d_in[2];
    const int*  eidx  = (const int*)d_in[3];
    const int*  batch = (const int*)d_in[4];
    const float* neW1=(const float*)d_in[5],  *neb1=(const float*)d_in[6],
               * neg1=(const float*)d_in[7],  *nebe1=(const float*)d_in[8];
    const float* neW2=(const float*)d_in[9],  *neb2=(const float*)d_in[10],
               * neg2=(const float*)d_in[11], *nebe2=(const float*)d_in[12];
    const float* eeW1=(const float*)d_in[13], *eeb1=(const float*)d_in[14];
    const float* eeW2=(const float*)d_in[15], *eeb2=(const float*)d_in[16];
    const float* ivW =(const float*)d_in[17], *ivb =(const float*)d_in[18];
    const float* cWma=(const float*)d_in[19], *cWmb=(const float*)d_in[20],
               * cWme=(const float*)d_in[21], *cbm =(const float*)d_in[22];
    const float* cWsx=(const float*)d_in[23], *cWsa=(const float*)d_in[24],
               * cbs =(const float*)d_in[25];
    const float* cWv1=(const float*)d_in[26], *cbv1=(const float*)d_in[27],
               * cWv2=(const float*)d_in[28], *cbv2=(const float*)d_in[29];
    const float* lng =(const float*)d_in[30], *lnb =(const float*)d_in[31],
               * vsg =(const float*)d_in[32];
    const float* pcW =(const float*)d_in[33], *pcb =(const float*)d_in[34];
    const float* pvW =(const float*)d_in[35];
    const float* sW  =(const float*)d_in[36];
    const float* aW  =(const float*)d_in[37], *ab  =(const float*)d_in[38];
    const float* pW1 =(const float*)d_in[39], *pb1 =(const float*)d_in[40],
               * pg1 =(const float*)d_in[41], *pbe1=(const float*)d_in[42];
    const float* pW2 =(const float*)d_in[43], *pb2 =(const float*)d_in[44],
               * pg2 =(const float*)d_in[45], *pbe2=(const float*)d_in[46];
    const float* pW3 =(const float*)d_in[47], *pb3 =(const float*)d_in[48];

    const int* src = eidx;
    const int* dst = eidx + NE;

    char* wp = (char*)d_ws;
    auto alloc = [&](size_t bytes)->char*{
        char* p = wp;
        wp += (bytes + 255) & ~(size_t)255;
        return p;
    };
    bf16*  bufM  = (bf16*) alloc((size_t)ECM*HD*2);       // 13.63 MB
    bf16*  bufG  = (bf16*) alloc((size_t)ECM*HD*2);       // 13.63 MB
    float* xs    = (float*)alloc((size_t)NN*HD*4);        // 25.6 MB
    float* xvA   = (float*)alloc((size_t)NN*3*HD*4);      // 76.8 MB
    float* xvB   = (float*)alloc((size_t)NN*3*HD*4);      // 76.8 MB
    bf16*  An    = (bf16*) alloc((size_t)NN*HD*2);        // 12.8 MB
    bf16*  Bn    = (bf16*) alloc((size_t)NN*HD*2);        // 12.8 MB
    bf16*  WtH   = (bf16*) alloc((size_t)7*HD*HD*2);      // 0.22 MB
    bf16*  WtL   = (bf16*) alloc((size_t)7*HD*HD*2);      // 0.22 MB
    float* Ubuf  = (float*)alloc((size_t)NB*HD*4);
    int* rowptr  = (int*)alloc((size_t)(NN+1)*4);
    int* cnt     = (int*)alloc((size_t)NN*4);
    int* elist   = (int*)alloc((size_t)NE*4);
    int* srcp    = (int*)alloc((size_t)NE*4);
    int* dstp    = (int*)alloc((size_t)NE*4);
    int* gptr    = (int*)alloc((size_t)(NB+1)*4);
    size_t used  = (size_t)(wp - (char*)d_ws);            // ~240.5 MB

    if (used > ws_size){
        sentinel_k<<<1, NB, 0, stream>>>((float*)d_out, -1.f - (float)(ws_size >> 20));
        return;
    }
    float* tmpF = xvB;
    bf16*  ubuf = An;

    // ---- CSR + gptr + weight splits ----
    hipMemsetAsync(cnt, 0, (size_t)NN*4, stream);
    hist_kernel<<<(NE+255)/256, 256, 0, stream>>>(dst, cnt, NE, NN);
    scan_kernel<<<1, 256, 0, stream>>>(cnt, rowptr, NN);
    hipMemsetAsync(cnt, 0, (size_t)NN*4, stream);
    fill_kernel<<<(NE+255)/256, 256, 0, stream>>>(src, dst, rowptr, cnt, elist, srcp, dstp, NE);
    gptr_kernel<<<(NN+255)/256, 256, 0, stream>>>(batch, gptr);
    wprep<<<64,256,0,stream>>>(eeW2, WtH, WtL);                        // mat 0
    for (int l=0;l<3;++l){
        wprep<<<64,256,0,stream>>>(cWme + (size_t)l*HD*HD, WtH + (size_t)(1+l)*HD*HD,
                                   WtL + (size_t)(1+l)*HD*HD);         // mats 1..3
        wprep<<<64,256,0,stream>>>(cWv1 + (size_t)l*HD*HD, WtH + (size_t)(4+l)*HD*HD,
                                   WtL + (size_t)(4+l)*HD*HD);         // mats 4..6
    }

    const int GN = (NN+63)/64;
    const int GE = ECM/64;
    const int GS = (CN+NPB-1)/NPB;

    // ---- node embeddings ----
    gemmk<M_BNSILU><<<GN,256,0,stream>>>(x, neW1, neb1, neg1, nebe1, tmpF, 0, NN, 92);
    gemmk<M_BNSILU><<<GN,256,0,stream>>>(tmpF, neW2, neb2, neg2, nebe2, xs, 0, NN, 128);
    gemmk<M_BIAS><<<GN,256,0,stream>>>(xs, ivW, ivb, nullptr, nullptr, tmpF, 0, NN, 128);
    xv_init<<<NN, 128, 0, stream>>>(tmpF, pos, xvA);

    // ---- message-passing layers ----
    float* xvO = xvA;
    float* xvN = xvB;
    for (int l=0; l<3; ++l){
        const float* Wma = cWma + (size_t)l*HD*HD;
        const float* Wmb = cWmb + (size_t)l*HD*HD;
        const float* bm  = cbm  + (size_t)l*HD;
        const float* Wsx = cWsx + (size_t)l*HD*HD;
        const float* Wsa = cWsa + (size_t)l*HD*HD;
        const float* bs  = cbs  + (size_t)l*HD;
        const float* bv1 = cbv1 + (size_t)l*HD;
        const float* Wv2 = cWv2 + (size_t)l*HD*HD;
        const float* bv2 = cbv2 + (size_t)l*HD;
        const bf16* W2h  = WtH;
        const bf16* W2l  = WtL;
        const bf16* Wmeh = WtH + (size_t)(1+l)*HD*HD;
        const bf16* Wmel = WtL + (size_t)(1+l)*HD*HD;
        const bf16* Wv1h = WtH + (size_t)(4+l)*HD*HD;
        const bf16* Wv1l = WtL + (size_t)(4+l)*HD*HD;

        gemmk<M_PLAIN><<<GN,256,0,stream>>>(xs, Wma, nullptr, nullptr, nullptr, An, 1, NN, 128);
        gemmk<M_PLAIN><<<GN,256,0,stream>>>(xs, Wmb, nullptr, nullptr, nullptr, Bn, 1, NN, 128);

        for (int c=0; c<NCH; ++c){
            int n0 = c*CN, n1 = n0+CN;
            edge_pipe<<<GE,256,0,stream>>>(eat, elist, srcp, dstp,
                                           eeW1, eeb1,
                                           W2h, W2l, eeb2,
                                           Wmeh, Wmel, bm,
                                           An, Bn,
                                           Wv1h, Wv1l, bv1,
                                           rowptr, n0, n1, bufM, bufG);
            su_fused<<<GS,128,0,stream>>>(rowptr, srcp, pos, bufM, bufG,
                                          xvO, xvN, xs,
                                          Wv2, bv2, Wsx, Wsa, bs,
                                          lng + (size_t)l*HD, lnb + (size_t)l*HD,
                                          vsg + (size_t)l*HD, l>0 ? 1 : 0, n0, n1);
        }
        float* t = xvO; xvO = xvN; xvN = t;
    }

    // ---- capsules & head ----
    capsule_u<<<NN, 128, 0, stream>>>(xs, xvO, pcW, pcb, pvW, ubuf);
    pool_u<<<NB, 128, 0, stream>>>(gptr, ubuf, Ubuf);
    graph_head<<<NB, 256, 0, stream>>>(Ubuf, sW, aW, ab,
                                       pW1, pb1, pg1, pbe1,
                                       pW2, pb2, pg2, pbe2,
                                       pW3, pb3, (float*)d_out);
}

// Round 12
// 4654.667 us; speedup vs baseline: 2.3665x; 1.2371x over previous
//
#include <hip/hip_runtime.h>
#include <hip/hip_bf16.h>
#include <math.h>

#define NN 50000
#define NE 400000
#define HD 128
#define NB 64
#define NCH 8
#define CN 6250          // nodes per chunk
#define ECM 53248        // max edges per chunk
#define NPB 8            // nodes per block in su_fused
#define PSL 16           // pool slices

typedef __hip_bfloat16 bf16;
typedef __attribute__((ext_vector_type(4))) unsigned short us4;
typedef __attribute__((ext_vector_type(8))) short s8v;    // 8 bf16 MFMA frag
typedef __attribute__((ext_vector_type(4))) float f4v;    // MFMA accumulator

__device__ __forceinline__ float sigm_(float x){ return 1.f/(1.f+__expf(-x)); }
__device__ __forceinline__ float silu_(float x){ return x*sigm_(x); }
__device__ __forceinline__ float bf2f(bf16 x){ return __bfloat162float(x); }
__device__ __forceinline__ unsigned short f2bu(float f){
    bf16 h = __float2bfloat16(f);
    return *reinterpret_cast<unsigned short*>(&h);
}
__device__ __forceinline__ bool finite_(float v){ return fabsf(v) <= 1e37f; }

enum { M_PLAIN=0, M_BIAS, M_BNSILU };

// ---------------- split-transpose weight prep: W[k][n](128x128) -> H/L[n][k] ----------
__global__ void wprep(const float* __restrict__ W, bf16* __restrict__ H, bf16* __restrict__ L){
    int i = blockIdx.x*256 + threadIdx.x;       // 16384 elements
    int k = i >> 7, n = i & 127;
    float w = W[i];
    bf16 h = __float2bfloat16(w);
    float r = w - bf2f(h);
    H[n*128 + k] = h;
    L[n*128 + k] = __float2bfloat16(r);
}

// W1[41][128] -> H/L[n][k] with K padded to 64
__global__ void wprep1(const float* __restrict__ W, bf16* __restrict__ H, bf16* __restrict__ L){
    int i = blockIdx.x*256 + threadIdx.x;       // 8192 elements
    int n = i >> 6, k = i & 63;
    float w = (k < 41) ? W[(size_t)k*HD + n] : 0.f;
    bf16 h = __float2bfloat16(w);
    float r = w - bf2f(h);
    H[n*64 + k] = h;
    L[n*64 + k] = __float2bfloat16(r);
}

// ---------------- generic tiled GEMM: C[M,128] = epilogue(A[M,K] @ W[K,128]) ----------
template<int MODE>
__global__ __launch_bounds__(256)
void gemmk(const float* __restrict__ A, const float* __restrict__ W,
           const float* __restrict__ bias, const float* __restrict__ gg,
           const float* __restrict__ be, void* __restrict__ Cv, int owf, int M, int K)
{
    const int row0 = blockIdx.x * 64;
    if (row0 >= M) return;
    __shared__ float As[32][68];
    __shared__ float Ws[32][128];
    const int tid = threadIdx.x;
    const int tx = tid & 15, ty = tid >> 4;
    const int col0 = tx*8;
    float acc[4][8];
#pragma unroll
    for (int r=0;r<4;++r)
#pragma unroll
        for (int j=0;j<8;++j) acc[r][j]=0.f;
    const int mload = tid >> 2;
    const int kload = (tid & 3) << 3;
    const int grow = row0 + mload;
    const bool rv = grow < M;

    for (int k0 = 0; k0 < K; k0 += 32) {
        if (rv && ((K & 3) == 0) && (k0 + kload + 8 <= K)) {
            const float* ap = A + (size_t)grow*K + k0 + kload;
            float4 v0 = *(const float4*)ap;
            float4 v1 = *(const float4*)(ap+4);
            As[kload+0][mload]=v0.x; As[kload+1][mload]=v0.y;
            As[kload+2][mload]=v0.z; As[kload+3][mload]=v0.w;
            As[kload+4][mload]=v1.x; As[kload+5][mload]=v1.y;
            As[kload+6][mload]=v1.z; As[kload+7][mload]=v1.w;
        } else {
#pragma unroll
            for (int j=0;j<8;++j){
                int kg = k0 + kload + j;
                As[kload+j][mload] = (rv && kg<K) ? A[(size_t)grow*K+kg] : 0.f;
            }
        }
        if (k0 + 32 <= K) {
#pragma unroll
            for (int j=0;j<4;++j){
                int el = (tid + j*256)*4;
                int kk = el >> 7, col = el & 127;
                *(float4*)&Ws[kk][col] = *(const float4*)&W[(size_t)(k0+kk)*HD + col];
            }
        } else {
#pragma unroll
            for (int j=0;j<16;++j){
                int el = tid*16 + j;
                int kk = el >> 7, col = el & 127;
                int kg = k0 + kk;
                Ws[kk][col] = (kg < K) ? W[(size_t)kg*HD + col] : 0.f;
            }
        }
        __syncthreads();
#pragma unroll
        for (int k=0;k<32;++k){
            float4 a4 = *(const float4*)&As[k][ty*4];
            float4 w0 = *(const float4*)&Ws[k][col0];
            float4 w1 = *(const float4*)&Ws[k][col0+4];
            float av[4] = {a4.x,a4.y,a4.z,a4.w};
            float wv[8] = {w0.x,w0.y,w0.z,w0.w,w1.x,w1.y,w1.z,w1.w};
#pragma unroll
            for (int r=0;r<4;++r)
#pragma unroll
                for (int j=0;j<8;++j) acc[r][j] += av[r]*wv[j];
        }
        __syncthreads();
    }
#pragma unroll
    for (int r=0;r<4;++r){
        int orow = row0 + ty*4 + r;
        if (orow >= M) continue;
        float o[8];
#pragma unroll
        for (int j=0;j<8;++j) o[j]=acc[r][j];
        if constexpr (MODE==M_BIAS || MODE==M_BNSILU){
#pragma unroll
            for (int j=0;j<8;++j) o[j] += bias[col0+j];
        }
        if constexpr (MODE==M_BNSILU){
#pragma unroll
            for (int j=0;j<8;++j) o[j] = silu_(o[j]*gg[col0+j] + be[col0+j]);
        }
        if (owf){
            bf16* C = (bf16*)Cv;
#pragma unroll
            for (int j=0;j<8;++j) C[(size_t)orow*HD+col0+j] = __float2bfloat16(o[j]);
        } else {
            float* C = (float*)Cv;
            float4* cp = (float4*)&C[(size_t)orow*HD + col0];
            cp[0] = make_float4(o[0],o[1],o[2],o[3]);
            cp[1] = make_float4(o[4],o[5],o[6],o[7]);
        }
    }
}

// ---------------- MFMA fused edge pipeline (all 4 GEMMs on matrix cores) ----------
__global__ __launch_bounds__(256)
void edge_pipe(const float* __restrict__ eat,
               const int* __restrict__ elist, const int* __restrict__ srcp,
               const int* __restrict__ dstp,
               const bf16* __restrict__ W1h, const bf16* __restrict__ W1l,
               const float* __restrict__ b1,
               const bf16* __restrict__ W2h, const bf16* __restrict__ W2l,
               const float* __restrict__ b2,
               const bf16* __restrict__ Wmeh, const bf16* __restrict__ Wmel,
               const float* __restrict__ bm,
               const bf16* __restrict__ An, const bf16* __restrict__ Bn,
               const bf16* __restrict__ Wv1h, const bf16* __restrict__ Wv1l,
               const float* __restrict__ bv1,
               const int* __restrict__ rp, int rn0, int rn1,
               bf16* __restrict__ outM, bf16* __restrict__ outG)
{
    __shared__ __align__(16) unsigned short T1[64][136];
    __shared__ __align__(16) unsigned short T2[64][136];
    __shared__ int elS[64], seS[64], deS[64];

    const int cbase = rp[rn0];
    const int Ml = min(ECM, max(rp[rn1]-cbase, 0));
    const int row0 = blockIdx.x*64;
    if (row0 >= Ml) return;
    const int tid = threadIdx.x;
    const int lane = tid & 63, wave = tid >> 6;
    const int quad = lane >> 4, n16 = lane & 15;
    const int cwb = wave*32;

    if (tid < 64){
        int r = row0 + tid;
        bool v = r < Ml;
        int p = cbase + (v ? r : 0);
        elS[tid] = v ? min(max(elist[p],0),NE-1) : 0;
        seS[tid] = v ? srcp[p] : 0;
        deS[tid] = v ? dstp[p] : 0;
    }
    __syncthreads();

    f4v acc[4][2];

    // ---------- G1: e1 = silu(eat[elist] @ W1 + b1), K=64(padded), split MFMA ------
    {
        s8v B1h[2][2], B1l[2][2];
#pragma unroll
        for (int ct=0; ct<2; ++ct){
            int nn = cwb + ct*16 + n16;
#pragma unroll
            for (int kc=0; kc<2; ++kc){
                B1h[ct][kc] = *(const s8v*)&W1h[(size_t)nn*64 + kc*32 + quad*8];
                B1l[ct][kc] = *(const s8v*)&W1l[(size_t)nn*64 + kc*32 + quad*8];
            }
        }
#pragma unroll
        for (int rt=0;rt<4;++rt)
#pragma unroll
            for (int ct=0;ct<2;++ct) acc[rt][ct] = (f4v){0.f,0.f,0.f,0.f};

#pragma unroll
        for (int rt=0; rt<4; ++rt){
            int arow = elS[rt*16 + n16];
#pragma unroll
            for (int kc=0; kc<2; ++kc){
                s8v ah, al;
#pragma unroll
                for (int j=0;j<8;++j){
                    int k = kc*32 + quad*8 + j;
                    float v = (k < 41) ? eat[(size_t)arow*41 + k] : 0.f;
                    unsigned short h = f2bu(v);
                    ah[j] = (short)h;
                    al[j] = (short)f2bu(v - __uint_as_float(((unsigned)h)<<16));
                }
#pragma unroll
                for (int ct=0; ct<2; ++ct){
                    acc[rt][ct] = __builtin_amdgcn_mfma_f32_16x16x32_bf16(ah, B1h[ct][kc], acc[rt][ct], 0,0,0);
                    acc[rt][ct] = __builtin_amdgcn_mfma_f32_16x16x32_bf16(ah, B1l[ct][kc], acc[rt][ct], 0,0,0);
                    acc[rt][ct] = __builtin_amdgcn_mfma_f32_16x16x32_bf16(al, B1h[ct][kc], acc[rt][ct], 0,0,0);
                }
            }
        }
#pragma unroll
        for (int ct=0; ct<2; ++ct){
            int col = cwb + ct*16 + n16;
            float bc = b1[col];
#pragma unroll
            for (int rt=0; rt<4; ++rt)
#pragma unroll
                for (int i=0;i<4;++i)
                    T1[rt*16 + quad*4 + i][col] = f2bu(silu_(acc[rt][ct][i] + bc));
        }
    }
    __syncthreads();

    // ---------- phases 0..2 (K=128, split-bf16 weights) ----------
    s8v Bh[2][4], Bl[2][4];
    for (int ph=0; ph<3; ++ph){
        const bf16* WH = (ph==0)? W2h : (ph==1)? Wmeh : Wv1h;
        const bf16* WL = (ph==0)? W2l : (ph==1)? Wmel : Wv1l;
        const unsigned short (*Tin)[136] = (ph==1)? (const unsigned short(*)[136])T2
                                                  : (const unsigned short(*)[136])T1;
#pragma unroll
        for (int ct=0; ct<2; ++ct){
            int nn = cwb + ct*16 + n16;
            const s8v* hp = (const s8v*)&WH[(size_t)nn*128];
            const s8v* lp = (const s8v*)&WL[(size_t)nn*128];
#pragma unroll
            for (int kc=0; kc<4; ++kc){
                Bh[ct][kc] = hp[kc*4 + quad];
                Bl[ct][kc] = lp[kc*4 + quad];
            }
        }
#pragma unroll
        for (int rt=0;rt<4;++rt)
#pragma unroll
            for (int ct=0;ct<2;++ct) acc[rt][ct] = (f4v){0.f,0.f,0.f,0.f};

#pragma unroll
        for (int kc=0; kc<4; ++kc){
#pragma unroll
            for (int rt=0; rt<4; ++rt){
                s8v a = *(const s8v*)&Tin[rt*16 + n16][kc*32 + quad*8];
#pragma unroll
                for (int ct=0; ct<2; ++ct){
                    acc[rt][ct] = __builtin_amdgcn_mfma_f32_16x16x32_bf16(a, Bh[ct][kc], acc[rt][ct], 0,0,0);
                    acc[rt][ct] = __builtin_amdgcn_mfma_f32_16x16x32_bf16(a, Bl[ct][kc], acc[rt][ct], 0,0,0);
                }
            }
        }
        if (ph==0){
#pragma unroll
            for (int ct=0; ct<2; ++ct){
                int col = cwb + ct*16 + n16;
                float bc = b2[col];
#pragma unroll
                for (int rt=0; rt<4; ++rt)
#pragma unroll
                    for (int i=0;i<4;++i)
                        T2[rt*16 + quad*4 + i][col] = f2bu(silu_(acc[rt][ct][i] + bc));
            }
            __syncthreads();
        } else if (ph==1){
#pragma unroll
            for (int ct=0; ct<2; ++ct){
                int col = cwb + ct*16 + n16;
                float bc = bm[col];
#pragma unroll
                for (int rt=0; rt<4; ++rt)
#pragma unroll
                    for (int i=0;i<4;++i){
                        int row = rt*16 + quad*4 + i;
                        int se = seS[row], de = deS[row];
                        float v = silu_(acc[rt][ct][i] + bc
                                        + bf2f(An[(size_t)se*HD+col])
                                        + bf2f(Bn[(size_t)de*HD+col]));
                        T1[row][col] = f2bu(v);
                    }
            }
            __syncthreads();
            {
                int row = tid >> 2, seg = tid & 3;
                if (row0 + row < Ml){
                    const s8v* s = (const s8v*)&T1[row][seg*32];
                    s8v* d = (s8v*)&outM[(size_t)(row0+row)*HD + seg*32];
                    d[0]=s[0]; d[1]=s[1]; d[2]=s[2]; d[3]=s[3];
                }
            }
        } else {
#pragma unroll
            for (int ct=0; ct<2; ++ct){
                int col = cwb + ct*16 + n16;
                float bc = bv1[col];
#pragma unroll
                for (int rt=0; rt<4; ++rt)
#pragma unroll
                    for (int i=0;i<4;++i)
                        T2[rt*16 + quad*4 + i][col] = f2bu(acc[rt][ct][i] + bc);
            }
            __syncthreads();
            {
                int row = tid >> 2, seg = tid & 3;
                if (row0 + row < Ml){
                    const s8v* s = (const s8v*)&T2[row][seg*32];
                    s8v* d = (s8v*)&outG[(size_t)(row0+row)*HD + seg*32];
                    d[0]=s[0]; d[1]=s[1]; d[2]=s[2]; d[3]=s[3];
                }
            }
        }
    }
}

// ---------------- fused scatter + GEMVs + layernorm/update ----------------
__global__ __launch_bounds__(128)
void su_fused(const int* __restrict__ rp, const int* __restrict__ srcp,
              const float* __restrict__ pos,
              const bf16* __restrict__ mB, const bf16* __restrict__ gB,
              const float* __restrict__ xvO, float* __restrict__ xvN,
              float* __restrict__ xs,
              const float* __restrict__ Wv2, const float* __restrict__ bv2,
              const float* __restrict__ Wsx, const float* __restrict__ Wsa,
              const float* __restrict__ bs,
              const float* __restrict__ lng, const float* __restrict__ lnb,
              const float* __restrict__ vsg, int addRes, int n0, int n1)
{
    __shared__ float mdS[NPB][3][128];
    __shared__ float smS[NPB][128];
    __shared__ float xsS[NPB][128];
    __shared__ float red[4];
    __shared__ float red2[2];
    const int h = threadIdx.x;
    const int base = n0 + blockIdx.x*NPB;
    const int cbase = rp[n0];
    float av0[NPB],av1[NPB],av2[NPB],sd0[NPB],sd1[NPB],sd2[NPB];
#pragma unroll
    for (int i=0;i<NPB;++i){
        int n = base+i;
        bool valid = n < n1;
        float sm=0,a0=0,a1=0,a2=0,m0=0,m1=0,m2=0,d0s=0,d1s=0,d2s=0;
        if (valid){
            int p0=rp[n], p1=rp[n+1];
            float px0=pos[n*3],px1=pos[n*3+1],px2=pos[n*3+2];
            for (int p=p0;p<p1;++p){
                int ii=p-cbase; if ((unsigned)ii>=(unsigned)ECM) break;
                float mh=bf2f(mB[(size_t)ii*HD+h]);
                float gh=bf2f(gB[(size_t)ii*HD+h]);
                int sn=srcp[p]; sn=min(max(sn,0),NN-1);
                float d0=px0-pos[sn*3], d1=px1-pos[sn*3+1], d2=px2-pos[sn*3+2];
                sm+=mh;
                a0+=xvO[(size_t)sn*3*HD+h]*gh;
                a1+=xvO[(size_t)sn*3*HD+HD+h]*gh;
                a2+=xvO[(size_t)sn*3*HD+2*HD+h]*gh;
                m0+=mh*d0; m1+=mh*d1; m2+=mh*d2;
                d0s+=d0; d1s+=d1; d2s+=d2;
            }
        }
        mdS[i][0][h]=m0; mdS[i][1][h]=m1; mdS[i][2][h]=m2;
        smS[i][h]=sm;
        xsS[i][h]= valid ? xs[(size_t)n*HD+h] : 0.f;
        av0[i]=a0; av1[i]=a1; av2[i]=a2; sd0[i]=d0s; sd1[i]=d1s; sd2[i]=d2s;
    }
    __syncthreads();
    float g0[NPB],g1v[NPB],g2[NPB],xw[NPB],sw[NPB];
#pragma unroll
    for (int i=0;i<NPB;++i){ g0[i]=0;g1v[i]=0;g2[i]=0;xw[i]=0;sw[i]=0; }
    for (int k=0;k<HD;++k){
        float w2=Wv2[k*HD+h], wx=Wsx[k*HD+h], wa=Wsa[k*HD+h];
#pragma unroll
        for (int i=0;i<NPB;++i){
            g0[i]+=mdS[i][0][k]*w2;
            g1v[i]+=mdS[i][1][k]*w2;
            g2[i]+=mdS[i][2][k]*w2;
            xw[i]+=xsS[i][k]*wx;
            sw[i]+=smS[i][k]*wa;
        }
    }
    const float b2v=bv2[h], bsv=bs[h], lgv=lng[h], lbv=lnb[h], vgv=vsg[h];
    const int w = h >> 6;
    for (int i=0;i<NPB;++i){
        int n = base+i;
        bool valid = n < n1;
        float xc = xw[i]+sw[i]+bsv;
        float s1=xc, s2=xc*xc;
#pragma unroll
        for (int off=1; off<64; off<<=1){ s1+=__shfl_xor(s1,off,64); s2+=__shfl_xor(s2,off,64); }
        if ((h&63)==0){ red[w*2]=s1; red[w*2+1]=s2; }
        __syncthreads();
        s1=red[0]+red[2]; s2=red[1]+red[3];
        float mu=s1*(1.f/128.f);
        float var=fmaxf(s2*(1.f/128.f)-mu*mu, 0.f);
        float xn=(xc-mu)*rsqrtf(var+1e-5f)*lgv+lbv;
        float ov0=0,ov1=0,ov2=0;
        if (valid){
            ov0=xvO[(size_t)n*3*HD+h];
            ov1=xvO[(size_t)n*3*HD+HD+h];
            ov2=xvO[(size_t)n*3*HD+2*HD+h];
        }
        float v0=ov0+av0[i]+g0[i]+b2v*sd0[i];
        float v1=ov1+av1[i]+g1v[i]+b2v*sd1[i];
        float v2=ov2+av2[i]+g2[i]+b2v*sd2[i];
        float q=v0*v0+v1*v1+v2*v2;
#pragma unroll
        for (int off=1; off<64; off<<=1) q+=__shfl_xor(q,off,64);
        if ((h&63)==0) red2[w]=q;
        __syncthreads();
        q=fmaxf(red2[0]+red2[1], 0.f);
        float nrm=sqrtf(q*(1.f/128.f)+1e-5f);
        float scale=vgv*sigm_(xn)/nrm;
        float r0=v0*scale, r1=v1*scale, r2=v2*scale;
        float nxs=silu_(xn);
        if (addRes){ nxs+=xsS[i][h]; r0+=ov0; r1+=ov1; r2+=ov2; }
        if (valid){
            xs[(size_t)n*HD+h]=nxs;
            xvN[(size_t)n*3*HD+h]=r0;
            xvN[(size_t)n*3*HD+HD+h]=r1;
            xvN[(size_t)n*3*HD+2*HD+h]=r2;
        }
        __syncthreads();
    }
}

// ---------------- CSR build ----------------
__global__ void hist_kernel(const int* __restrict__ idx, int* __restrict__ cnt, int n, int nb){
    int i = blockIdx.x*256 + threadIdx.x;
    if (i < n){
        int v = idx[i]; v = min(max(v,0), nb-1);
        atomicAdd(&cnt[v], 1);
    }
}

__global__ void scan_kernel(const int* __restrict__ cnt, int* __restrict__ out, int n){
    __shared__ int sums[256];
    int t = threadIdx.x;
    int chunk = (n + 255) / 256;
    int lo = t*chunk, hi = lo+chunk; if (hi > n) hi = n; if (lo > n) lo = n;
    int s = 0;
    for (int i=lo;i<hi;++i) s += cnt[i];
    sums[t] = s;
    __syncthreads();
    if (t==0){ int run=0; for (int i=0;i<256;++i){ int v=sums[i]; sums[i]=run; run+=v; } }
    __syncthreads();
    int run = sums[t];
    for (int i=lo;i<hi;++i){ out[i]=run; run+=cnt[i]; }
    if (hi == n) out[n] = run;
}

__global__ void fill_kernel(const int* __restrict__ src, const int* __restrict__ dst,
                            const int* __restrict__ rowptr, int* __restrict__ cur,
                            int* __restrict__ elist, int* __restrict__ srcp,
                            int* __restrict__ dstp, int n){
    int e = blockIdx.x*256 + threadIdx.x;
    if (e < n){
        int d = dst[e]; d = min(max(d,0), NN-1);
        int slot = atomicAdd(&cur[d], 1);
        int p = rowptr[d] + slot;
        if (p >= 0 && p < NE){
            elist[p] = e;
            int s = src[e];
            srcp[p] = min(max(s,0), NN-1);
            dstp[p] = d;
        }
    }
}

__global__ void gptr_kernel(const int* __restrict__ batch, int* __restrict__ gptr){
    int n = blockIdx.x*256 + threadIdx.x;
    if (n >= NN) return;
    int b = batch[n]; b = min(max(b,0), NB-1);
    if (n == 0){
        for (int g=0; g<=b; ++g) gptr[g] = 0;
    } else {
        int bp = batch[n-1]; bp = min(max(bp,0), NB-1);
        for (int g=bp+1; g<=b; ++g) gptr[g] = n;
    }
    if (n == NN-1){
        for (int g=b+1; g<=NB; ++g) gptr[g] = NN;
    }
}

__global__ void xv_init(const float* __restrict__ xw, const float* __restrict__ pos,
                        float* __restrict__ xv){
    int n = blockIdx.x, h = threadIdx.x;
    float v = xw[(size_t)n*HD+h];
    xv[(size_t)n*3*HD + h]        = v*pos[n*3+0];
    xv[(size_t)n*3*HD + HD + h]   = v*pos[n*3+1];
    xv[(size_t)n*3*HD + 2*HD + h] = v*pos[n*3+2];
}

// capsule math from precomputed P (fp32) + xv
__global__ __launch_bounds__(128)
void capsule2(const float* __restrict__ Pf, const float* __restrict__ xv,
              const float* __restrict__ pvW, bf16* __restrict__ u){
    __shared__ float Pn[128];
    __shared__ float Xv[3][128];
    __shared__ float dots[48];
    __shared__ float pvn[16];
    __shared__ float capn2[8];
    int n = blockIdx.x, t = threadIdx.x;
    Pn[t] = Pf[(size_t)n*HD + t];
    Xv[0][t] = xv[(size_t)n*3*HD + t];
    Xv[1][t] = xv[(size_t)n*3*HD + HD + t];
    Xv[2][t] = xv[(size_t)n*3*HD + 2*HD + t];
    __syncthreads();
    if (t < 48){
        int pp = t/3, c = t%3;
        float a = 0.f;
        for (int hh=0; hh<128; ++hh) a += Xv[c][hh]*pvW[hh*16+pp];
        dots[t] = a;
    }
    if (t < 8){
        float a = 0.f;
        for (int d=0; d<16; ++d){ float x = Pn[t*16+d]; a += x*x; }
        capn2[t] = a;
    }
    __syncthreads();
    if (t < 16){
        float a = dots[t*3]*dots[t*3] + dots[t*3+1]*dots[t*3+1] + dots[t*3+2]*dots[t*3+2];
        pvn[t] = sqrtf(a + 1e-9f);
    }
    __syncthreads();
    int cap = t >> 4, d = t & 15;
    float n2 = capn2[cap];
    float pcv = Pn[t] * (n2/(1.f+n2)) * rsqrtf(n2 + 1e-9f);
    u[(size_t)n*HD + t] = __float2bfloat16(pcv + pvn[d]);
}

// two-stage pooling
__global__ void pool1(const int* __restrict__ gptr, const bf16* __restrict__ u,
                      float* __restrict__ Up){
    int blk = blockIdx.x;            // b*PSL + s
    int b = blk / PSL, s = blk % PSL;
    int h = threadIdx.x;
    int g0 = gptr[b], g1 = gptr[b+1];
    g0 = min(max(g0,0), NN); g1 = min(max(g1,0), NN);
    const int SL = (NN + PSL - 1) / PSL;
    int lo = max(g0, s*SL), hi = min(g1, (s+1)*SL);
    float a = 0.f;
    for (int n=lo; n<hi; ++n) a += bf2f(u[(size_t)n*HD + h]);
    Up[(size_t)blk*HD + h] = a;
}

__global__ void pool2(const float* __restrict__ Up, float* __restrict__ U){
    int b = blockIdx.x, h = threadIdx.x;
    float a = 0.f;
    for (int s=0; s<PSL; ++s) a += Up[(size_t)(b*PSL+s)*HD + h];
    U[b*HD + h] = a;
}

__global__ void graph_head(const float* __restrict__ U, const float* __restrict__ sW,
                           const float* __restrict__ aW, const float* __restrict__ ab,
                           const float* __restrict__ pW1, const float* __restrict__ pb1,
                           const float* __restrict__ pg1, const float* __restrict__ pbe1,
                           const float* __restrict__ pW2, const float* __restrict__ pb2,
                           const float* __restrict__ pg2, const float* __restrict__ pbe2,
                           const float* __restrict__ pW3, const float* __restrict__ pb3,
                           float* __restrict__ out){
    __shared__ float Ub[128];
    __shared__ float pooled[2048];
    __shared__ float vv[256];
    __shared__ float bbs[64], ccs[64];
    __shared__ float lg[8], aws[8];
    __shared__ float wcs[32];
    __shared__ float h1[64], h2[32];
    int b = blockIdx.x, t = threadIdx.x;
    if (t < 128) Ub[t] = U[b*HD + t];
    __syncthreads();
#pragma unroll
    for (int j=0;j<8;++j){
        int o = t + 256*j;
        int p = o >> 8, c = (o >> 5) & 7, e = o & 31;
        float a = 0.f;
#pragma unroll
        for (int d=0; d<16; ++d) a += Ub[p*16+d]*sW[((p*16+d)*8+c)*32+e];
        pooled[o] = a;
    }
    __syncthreads();
    {
        float s = 0.f;
        for (int p=0;p<8;++p) s += pooled[p*256 + t];
        s *= 0.125f;
        float n2 = s*s;
#pragma unroll
        for (int off=1; off<32; off<<=1) n2 += __shfl_xor(n2,off,32);
        vv[t] = s*(n2/(1.f+n2))*rsqrtf(n2+1e-9f);
    }
    __syncthreads();
    if (t < 64){
        int p = t>>3, c = t&7;
        float a = 0.f;
        for (int e=0;e<32;++e) a += pooled[p*256+c*32+e]*vv[c*32+e];
        bbs[t] = a;
    }
    __syncthreads();
    if (t < 64){
        int p = t>>3;
        float mx = -1e30f;
        for (int j=0;j<8;++j) mx = fmaxf(mx, bbs[p*8+j]);
        float sum = 0.f;
        for (int j=0;j<8;++j) sum += __expf(bbs[p*8+j]-mx);
        ccs[t] = __expf(bbs[t]-mx)/sum;
    }
    __syncthreads();
    {
        int c = t>>5;
        float s = 0.f;
        for (int p=0;p<8;++p) s += ccs[p*8+c]*pooled[p*256 + t];
        float n2 = s*s;
#pragma unroll
        for (int off=1; off<32; off<<=1) n2 += __shfl_xor(n2,off,32);
        vv[t] = s*(n2/(1.f+n2))*rsqrtf(n2+1e-9f);
    }
    __syncthreads();
    if (t < 8){
        float a = 0.f;
        for (int j=0;j<16;++j) a += vv[t*32+j]*aW[j];
        lg[t] = a + ab[0];
    }
    __syncthreads();
    if (t < 8){
        float mx = -1e30f;
        for (int j=0;j<8;++j) mx = fmaxf(mx, lg[j]);
        float sum = 0.f;
        for (int j=0;j<8;++j) sum += __expf(lg[j]-mx);
        aws[t] = __expf(lg[t]-mx)/sum;
    }
    __syncthreads();
    if (t < 32){
        float a = 0.f;
        for (int c=0;c<8;++c) a += aws[c]*vv[c*32+t];
        wcs[t] = a;
    }
    __syncthreads();
    if (t < 64){
        float a = 0.f;
        for (int e=0;e<32;++e) a += wcs[e]*pW1[e*64+t];
        h1[t] = silu_((a+pb1[t])*pg1[t]+pbe1[t]);
    }
    __syncthreads();
    if (t < 32){
        float a = 0.f;
        for (int j=0;j<64;++j) a += h1[j]*pW2[j*32+t];
        h2[t] = silu_((a+pb2[t])*pg2[t]+pbe2[t]);
    }
    __syncthreads();
    if (t == 0){
        float a = 0.f;
        for (int j=0;j<32;++j) a += h2[j]*pW3[j];
        a += pb3[0];
        if (!finite_(a)) a = 999.f;
        out[b] = a;
    }
}

__global__ void sentinel_k(float* __restrict__ out, float v){
    out[threadIdx.x] = v;
}

// ---------------- host side ----------------
extern "C" void kernel_launch(void* const* d_in, const int* in_sizes, int n_in,
                              void* d_out, int out_size, void* d_ws, size_t ws_size,
                              hipStream_t stream)
{
    (void)in_sizes; (void)n_in; (void)out_size;
    const float* x    = (const float*)d_in[0];
    const float* eat  = (const float*)d_in[1];
    const float* pos  = (const float*)d_in[2];
    const int*  eidx  = (const int*)d_in[3];
    const int*  batch = (const int*)d_in[4];
    const float* neW1=(const float*)d_in[5],  *neb1=(const float*)d_in[6],
               * neg1=(const float*)d_in[7],  *nebe1=(const float*)d_in[8];
    const float* neW2=(const float*)d_in[9],  *neb2=(const float*)d_in[10],
               * neg2=(const float*)d_in[11], *nebe2=(const float*)d_in[12];
    const float* eeW1=(const float*)d_in[13], *eeb1=(const float*)d_in[14];
    const float* eeW2=(const float*)d_in[15], *eeb2=(const float*)d_in[16];
    const float* ivW =(const float*)d_in[17], *ivb =(const float*)d_in[18];
    const float* cWma=(const float*)d_in[19], *cWmb=(const float*)d_in[20],
               * cWme=(const float*)d_in[21], *cbm =(const float*)d_in[22];
    const float* cWsx=(const float*)d_in[23], *cWsa=(const float*)d_in[24],
               * cbs =(const float*)d_in[25];
    const float* cWv1=(const float*)d_in[26], *cbv1=(const float*)d_in[27],
               * cWv2=(const float*)d_in[28], *cbv2=(const float*)d_in[29];
    const float* lng =(const float*)d_in[30], *lnb =(const float*)d_in[31],
               * vsg =(const float*)d_in[32];
    const float* pcW =(const float*)d_in[33], *pcb =(const float*)d_in[34];
    const float* pvW =(const float*)d_in[35];
    const float* sW  =(const float*)d_in[36];
    const float* aW  =(const float*)d_in[37], *ab  =(const float*)d_in[38];
    const float* pW1 =(const float*)d_in[39], *pb1 =(const float*)d_in[40],
               * pg1 =(const float*)d_in[41], *pbe1=(const float*)d_in[42];
    const float* pW2 =(const float*)d_in[43], *pb2 =(const float*)d_in[44],
               * pg2 =(const float*)d_in[45], *pbe2=(const float*)d_in[46];
    const float* pW3 =(const float*)d_in[47], *pb3 =(const float*)d_in[48];

    const int* src = eidx;
    const int* dst = eidx + NE;

    char* wp = (char*)d_ws;
    auto alloc = [&](size_t bytes)->char*{
        char* p = wp;
        wp += (bytes + 255) & ~(size_t)255;
        return p;
    };
    bf16*  bufM  = (bf16*) alloc((size_t)ECM*HD*2);
    bf16*  bufG  = (bf16*) alloc((size_t)ECM*HD*2);
    float* xs    = (float*)alloc((size_t)NN*HD*4);
    float* xvA   = (float*)alloc((size_t)NN*3*HD*4);
    float* xvB   = (float*)alloc((size_t)NN*3*HD*4);
    bf16*  An    = (bf16*) alloc((size_t)NN*HD*2);
    bf16*  Bn    = (bf16*) alloc((size_t)NN*HD*2);
    bf16*  WtH   = (bf16*) alloc((size_t)7*HD*HD*2);
    bf16*  WtL   = (bf16*) alloc((size_t)7*HD*HD*2);
    bf16*  W1h   = (bf16*) alloc((size_t)HD*64*2);
    bf16*  W1l   = (bf16*) alloc((size_t)HD*64*2);
    float* Up    = (float*)alloc((size_t)NB*PSL*HD*4);
    float* Ubuf  = (float*)alloc((size_t)NB*HD*4);
    int* rowptr  = (int*)alloc((size_t)(NN+1)*4);
    int* cnt     = (int*)alloc((size_t)NN*4);
    int* elist   = (int*)alloc((size_t)NE*4);
    int* srcp    = (int*)alloc((size_t)NE*4);
    int* dstp    = (int*)alloc((size_t)NE*4);
    int* gptr    = (int*)alloc((size_t)(NB+1)*4);
    size_t used  = (size_t)(wp - (char*)d_ws);   // ~241 MB

    if (used > ws_size){
        sentinel_k<<<1, NB, 0, stream>>>((float*)d_out, -1.f - (float)(ws_size >> 20));
        return;
    }
    float* tmpF = xvB;      // embeddings scratch
    bf16*  ubuf = An;       // capsule u
    float* Pf   = xvA;      // capsule P (xvA dead after layers; final xv in xvB)

    // ---- CSR + gptr + weight splits ----
    hipMemsetAsync(cnt, 0, (size_t)NN*4, stream);
    hist_kernel<<<(NE+255)/256, 256, 0, stream>>>(dst, cnt, NE, NN);
    scan_kernel<<<1, 256, 0, stream>>>(cnt, rowptr, NN);
    hipMemsetAsync(cnt, 0, (size_t)NN*4, stream);
    fill_kernel<<<(NE+255)/256, 256, 0, stream>>>(src, dst, rowptr, cnt, elist, srcp, dstp, NE);
    gptr_kernel<<<(NN+255)/256, 256, 0, stream>>>(batch, gptr);
    wprep1<<<32,256,0,stream>>>(eeW1, W1h, W1l);
    wprep<<<64,256,0,stream>>>(eeW2, WtH, WtL);
    for (int l=0;l<3;++l){
        wprep<<<64,256,0,stream>>>(cWme + (size_t)l*HD*HD, WtH + (size_t)(1+l)*HD*HD,
                                   WtL + (size_t)(1+l)*HD*HD);
        wprep<<<64,256,0,stream>>>(cWv1 + (size_t)l*HD*HD, WtH + (size_t)(4+l)*HD*HD,
                                   WtL + (size_t)(4+l)*HD*HD);
    }

    const int GN = (NN+63)/64;
    const int GE = ECM/64;
    const int GS = (CN+NPB-1)/NPB;

    // ---- node embeddings ----
    gemmk<M_BNSILU><<<GN,256,0,stream>>>(x, neW1, neb1, neg1, nebe1, tmpF, 0, NN, 92);
    gemmk<M_BNSILU><<<GN,256,0,stream>>>(tmpF, neW2, neb2, neg2, nebe2, xs, 0, NN, 128);
    gemmk<M_BIAS><<<GN,256,0,stream>>>(xs, ivW, ivb, nullptr, nullptr, tmpF, 0, NN, 128);
    xv_init<<<NN, 128, 0, stream>>>(tmpF, pos, xvA);

    // ---- message-passing layers ----
    float* xvO = xvA;
    float* xvN = xvB;
    for (int l=0; l<3; ++l){
        const float* Wma = cWma + (size_t)l*HD*HD;
        const float* Wmb = cWmb + (size_t)l*HD*HD;
        const float* bm  = cbm  + (size_t)l*HD;
        const float* Wsx = cWsx + (size_t)l*HD*HD;
        const float* Wsa = cWsa + (size_t)l*HD*HD;
        const float* bs  = cbs  + (size_t)l*HD;
        const float* bv1 = cbv1 + (size_t)l*HD;
        const float* Wv2 = cWv2 + (size_t)l*HD*HD;
        const float* bv2 = cbv2 + (size_t)l*HD;
        const bf16* Wmeh = WtH + (size_t)(1+l)*HD*HD;
        const bf16* Wmel = WtL + (size_t)(1+l)*HD*HD;
        const bf16* Wv1h = WtH + (size_t)(4+l)*HD*HD;
        const bf16* Wv1l = WtL + (size_t)(4+l)*HD*HD;

        gemmk<M_PLAIN><<<GN,256,0,stream>>>(xs, Wma, nullptr, nullptr, nullptr, An, 1, NN, 128);
        gemmk<M_PLAIN><<<GN,256,0,stream>>>(xs, Wmb, nullptr, nullptr, nullptr, Bn, 1, NN, 128);

        for (int c=0; c<NCH; ++c){
            int n0 = c*CN, n1 = n0+CN;
            edge_pipe<<<GE,256,0,stream>>>(eat, elist, srcp, dstp,
                                           W1h, W1l, eeb1,
                                           WtH, WtL, eeb2,
                                           Wmeh, Wmel, bm,
                                           An, Bn,
                                           Wv1h, Wv1l, bv1,
                                           rowptr, n0, n1, bufM, bufG);
            su_fused<<<GS,128,0,stream>>>(rowptr, srcp, pos, bufM, bufG,
                                          xvO, xvN, xs,
                                          Wv2, bv2, Wsx, Wsa, bs,
                                          lng + (size_t)l*HD, lnb + (size_t)l*HD,
                                          vsg + (size_t)l*HD, l>0 ? 1 : 0, n0, n1);
        }
        float* t = xvO; xvO = xvN; xvN = t;
    }

    // ---- capsules & head ----
    gemmk<M_BIAS><<<GN,256,0,stream>>>(xs, pcW, pcb, nullptr, nullptr, Pf, 0, NN, 128);
    capsule2<<<NN, 128, 0, stream>>>(Pf, xvO, pvW, ubuf);
    pool1<<<NB*PSL, 128, 0, stream>>>(gptr, ubuf, Up);
    pool2<<<NB, 128, 0, stream>>>(Up, Ubuf);
    graph_head<<<NB, 256, 0, stream>>>(Ubuf, sW, aW, ab,
                                       pW1, pb1, pg1, pbe1,
                                       pW2, pb2, pg2, pbe2,
                                       pW3, pb3, (float*)d_out);
}

// Round 13
// 4215.281 us; speedup vs baseline: 2.6132x; 1.1042x over previous
//
#include <hip/hip_runtime.h>
#include <hip/hip_bf16.h>
#include <math.h>

#define NN 50000
#define NE 400000
#define HD 128
#define NB 64
#define NCH 8
#define CN 6250          // nodes per chunk
#define ECM 53248        // max edges per chunk
#define NPB 8            // nodes per block in nu_fused
#define PSL 16           // pool slices

typedef __hip_bfloat16 bf16;
typedef __attribute__((ext_vector_type(4))) unsigned short us4;
typedef __attribute__((ext_vector_type(8))) short s8v;    // 8 bf16 MFMA frag
typedef __attribute__((ext_vector_type(4))) float f4v;    // MFMA accumulator

__device__ __forceinline__ float sigm_(float x){ return 1.f/(1.f+__expf(-x)); }
__device__ __forceinline__ float silu_(float x){ return x*sigm_(x); }
__device__ __forceinline__ float bf2f(bf16 x){ return __bfloat162float(x); }
__device__ __forceinline__ unsigned short f2bu(float f){
    bf16 h = __float2bfloat16(f);
    return *reinterpret_cast<unsigned short*>(&h);
}
__device__ __forceinline__ bool finite_(float v){ return fabsf(v) <= 1e37f; }

enum { M_PLAIN=0, M_BIAS, M_BNSILU };

// ---------------- split-transpose weight prep ----------------
__global__ void wprep(const float* __restrict__ W, bf16* __restrict__ H, bf16* __restrict__ L){
    int i = blockIdx.x*256 + threadIdx.x;
    int k = i >> 7, n = i & 127;
    float w = W[i];
    bf16 h = __float2bfloat16(w);
    float r = w - bf2f(h);
    H[n*128 + k] = h;
    L[n*128 + k] = __float2bfloat16(r);
}

__global__ void wprep1(const float* __restrict__ W, bf16* __restrict__ H, bf16* __restrict__ L){
    int i = blockIdx.x*256 + threadIdx.x;
    int n = i >> 6, k = i & 63;
    float w = (k < 41) ? W[(size_t)k*HD + n] : 0.f;
    bf16 h = __float2bfloat16(w);
    float r = w - bf2f(h);
    H[n*64 + k] = h;
    L[n*64 + k] = __float2bfloat16(r);
}

// ---------------- generic tiled GEMM ----------------
template<int MODE>
__global__ __launch_bounds__(256)
void gemmk(const float* __restrict__ A, const float* __restrict__ W,
           const float* __restrict__ bias, const float* __restrict__ gg,
           const float* __restrict__ be, void* __restrict__ Cv, int owf, int M, int K)
{
    const int row0 = blockIdx.x * 64;
    if (row0 >= M) return;
    __shared__ float As[32][68];
    __shared__ float Ws[32][128];
    const int tid = threadIdx.x;
    const int tx = tid & 15, ty = tid >> 4;
    const int col0 = tx*8;
    float acc[4][8];
#pragma unroll
    for (int r=0;r<4;++r)
#pragma unroll
        for (int j=0;j<8;++j) acc[r][j]=0.f;
    const int mload = tid >> 2;
    const int kload = (tid & 3) << 3;
    const int grow = row0 + mload;
    const bool rv = grow < M;

    for (int k0 = 0; k0 < K; k0 += 32) {
        if (rv && ((K & 3) == 0) && (k0 + kload + 8 <= K)) {
            const float* ap = A + (size_t)grow*K + k0 + kload;
            float4 v0 = *(const float4*)ap;
            float4 v1 = *(const float4*)(ap+4);
            As[kload+0][mload]=v0.x; As[kload+1][mload]=v0.y;
            As[kload+2][mload]=v0.z; As[kload+3][mload]=v0.w;
            As[kload+4][mload]=v1.x; As[kload+5][mload]=v1.y;
            As[kload+6][mload]=v1.z; As[kload+7][mload]=v1.w;
        } else {
#pragma unroll
            for (int j=0;j<8;++j){
                int kg = k0 + kload + j;
                As[kload+j][mload] = (rv && kg<K) ? A[(size_t)grow*K+kg] : 0.f;
            }
        }
        if (k0 + 32 <= K) {
#pragma unroll
            for (int j=0;j<4;++j){
                int el = (tid + j*256)*4;
                int kk = el >> 7, col = el & 127;
                *(float4*)&Ws[kk][col] = *(const float4*)&W[(size_t)(k0+kk)*HD + col];
            }
        } else {
#pragma unroll
            for (int j=0;j<16;++j){
                int el = tid*16 + j;
                int kk = el >> 7, col = el & 127;
                int kg = k0 + kk;
                Ws[kk][col] = (kg < K) ? W[(size_t)kg*HD + col] : 0.f;
            }
        }
        __syncthreads();
#pragma unroll
        for (int k=0;k<32;++k){
            float4 a4 = *(const float4*)&As[k][ty*4];
            float4 w0 = *(const float4*)&Ws[k][col0];
            float4 w1 = *(const float4*)&Ws[k][col0+4];
            float av[4] = {a4.x,a4.y,a4.z,a4.w};
            float wv[8] = {w0.x,w0.y,w0.z,w0.w,w1.x,w1.y,w1.z,w1.w};
#pragma unroll
            for (int r=0;r<4;++r)
#pragma unroll
                for (int j=0;j<8;++j) acc[r][j] += av[r]*wv[j];
        }
        __syncthreads();
    }
#pragma unroll
    for (int r=0;r<4;++r){
        int orow = row0 + ty*4 + r;
        if (orow >= M) continue;
        float o[8];
#pragma unroll
        for (int j=0;j<8;++j) o[j]=acc[r][j];
        if constexpr (MODE==M_BIAS || MODE==M_BNSILU){
#pragma unroll
            for (int j=0;j<8;++j) o[j] += bias[col0+j];
        }
        if constexpr (MODE==M_BNSILU){
#pragma unroll
            for (int j=0;j<8;++j) o[j] = silu_(o[j]*gg[col0+j] + be[col0+j]);
        }
        if (owf){
            bf16* C = (bf16*)Cv;
#pragma unroll
            for (int j=0;j<8;++j) C[(size_t)orow*HD+col0+j] = __float2bfloat16(o[j]);
        } else {
            float* C = (float*)Cv;
            float4* cp = (float4*)&C[(size_t)orow*HD + col0];
            cp[0] = make_float4(o[0],o[1],o[2],o[3]);
            cp[1] = make_float4(o[4],o[5],o[6],o[7]);
        }
    }
}

// ---------------- MFMA fused edge pipeline ----------------
__global__ __launch_bounds__(256)
void edge_pipe(const float* __restrict__ eat,
               const int* __restrict__ elist, const int* __restrict__ srcp,
               const int* __restrict__ dstp,
               const bf16* __restrict__ W1h, const bf16* __restrict__ W1l,
               const float* __restrict__ b1,
               const bf16* __restrict__ W2h, const bf16* __restrict__ W2l,
               const float* __restrict__ b2,
               const bf16* __restrict__ Wmeh, const bf16* __restrict__ Wmel,
               const float* __restrict__ bm,
               const bf16* __restrict__ An, const bf16* __restrict__ Bn,
               const bf16* __restrict__ Wv1h, const bf16* __restrict__ Wv1l,
               const float* __restrict__ bv1,
               const int* __restrict__ rp, int rn0, int rn1,
               bf16* __restrict__ outM, bf16* __restrict__ outG)
{
    __shared__ __align__(16) unsigned short T1[64][136];
    __shared__ __align__(16) unsigned short T2[64][136];
    __shared__ int elS[64], seS[64], deS[64];

    const int cbase = rp[rn0];
    const int Ml = min(ECM, max(rp[rn1]-cbase, 0));
    const int row0 = blockIdx.x*64;
    if (row0 >= Ml) return;
    const int tid = threadIdx.x;
    const int lane = tid & 63, wave = tid >> 6;
    const int quad = lane >> 4, n16 = lane & 15;
    const int cwb = wave*32;

    if (tid < 64){
        int r = row0 + tid;
        bool v = r < Ml;
        int p = cbase + (v ? r : 0);
        elS[tid] = v ? min(max(elist[p],0),NE-1) : 0;
        seS[tid] = v ? srcp[p] : 0;
        deS[tid] = v ? dstp[p] : 0;
    }
    __syncthreads();

    f4v acc[4][2];

    // ---------- G1: K=64(padded) split MFMA ----------
    {
        s8v B1h[2][2], B1l[2][2];
#pragma unroll
        for (int ct=0; ct<2; ++ct){
            int nn = cwb + ct*16 + n16;
#pragma unroll
            for (int kc=0; kc<2; ++kc){
                B1h[ct][kc] = *(const s8v*)&W1h[(size_t)nn*64 + kc*32 + quad*8];
                B1l[ct][kc] = *(const s8v*)&W1l[(size_t)nn*64 + kc*32 + quad*8];
            }
        }
#pragma unroll
        for (int rt=0;rt<4;++rt)
#pragma unroll
            for (int ct=0;ct<2;++ct) acc[rt][ct] = (f4v){0.f,0.f,0.f,0.f};

#pragma unroll
        for (int rt=0; rt<4; ++rt){
            int arow = elS[rt*16 + n16];
#pragma unroll
            for (int kc=0; kc<2; ++kc){
                s8v ah, al;
#pragma unroll
                for (int j=0;j<8;++j){
                    int k = kc*32 + quad*8 + j;
                    float v = (k < 41) ? eat[(size_t)arow*41 + k] : 0.f;
                    unsigned short h = f2bu(v);
                    ah[j] = (short)h;
                    al[j] = (short)f2bu(v - __uint_as_float(((unsigned)h)<<16));
                }
#pragma unroll
                for (int ct=0; ct<2; ++ct){
                    acc[rt][ct] = __builtin_amdgcn_mfma_f32_16x16x32_bf16(ah, B1h[ct][kc], acc[rt][ct], 0,0,0);
                    acc[rt][ct] = __builtin_amdgcn_mfma_f32_16x16x32_bf16(ah, B1l[ct][kc], acc[rt][ct], 0,0,0);
                    acc[rt][ct] = __builtin_amdgcn_mfma_f32_16x16x32_bf16(al, B1h[ct][kc], acc[rt][ct], 0,0,0);
                }
            }
        }
#pragma unroll
        for (int ct=0; ct<2; ++ct){
            int col = cwb + ct*16 + n16;
            float bc = b1[col];
#pragma unroll
            for (int rt=0; rt<4; ++rt)
#pragma unroll
                for (int i=0;i<4;++i)
                    T1[rt*16 + quad*4 + i][col] = f2bu(silu_(acc[rt][ct][i] + bc));
        }
    }
    __syncthreads();

    // ---------- phases 0..2 (K=128, split-bf16 weights) ----------
    s8v Bh[2][4], Bl[2][4];
    for (int ph=0; ph<3; ++ph){
        const bf16* WH = (ph==0)? W2h : (ph==1)? Wmeh : Wv1h;
        const bf16* WL = (ph==0)? W2l : (ph==1)? Wmel : Wv1l;
        const unsigned short (*Tin)[136] = (ph==1)? (const unsigned short(*)[136])T2
                                                  : (const unsigned short(*)[136])T1;
#pragma unroll
        for (int ct=0; ct<2; ++ct){
            int nn = cwb + ct*16 + n16;
            const s8v* hp = (const s8v*)&WH[(size_t)nn*128];
            const s8v* lp = (const s8v*)&WL[(size_t)nn*128];
#pragma unroll
            for (int kc=0; kc<4; ++kc){
                Bh[ct][kc] = hp[kc*4 + quad];
                Bl[ct][kc] = lp[kc*4 + quad];
            }
        }
#pragma unroll
        for (int rt=0;rt<4;++rt)
#pragma unroll
            for (int ct=0;ct<2;++ct) acc[rt][ct] = (f4v){0.f,0.f,0.f,0.f};

#pragma unroll
        for (int kc=0; kc<4; ++kc){
#pragma unroll
            for (int rt=0; rt<4; ++rt){
                s8v a = *(const s8v*)&Tin[rt*16 + n16][kc*32 + quad*8];
#pragma unroll
                for (int ct=0; ct<2; ++ct){
                    acc[rt][ct] = __builtin_amdgcn_mfma_f32_16x16x32_bf16(a, Bh[ct][kc], acc[rt][ct], 0,0,0);
                    acc[rt][ct] = __builtin_amdgcn_mfma_f32_16x16x32_bf16(a, Bl[ct][kc], acc[rt][ct], 0,0,0);
                }
            }
        }
        if (ph==0){
#pragma unroll
            for (int ct=0; ct<2; ++ct){
                int col = cwb + ct*16 + n16;
                float bc = b2[col];
#pragma unroll
                for (int rt=0; rt<4; ++rt)
#pragma unroll
                    for (int i=0;i<4;++i)
                        T2[rt*16 + quad*4 + i][col] = f2bu(silu_(acc[rt][ct][i] + bc));
            }
            __syncthreads();
        } else if (ph==1){
#pragma unroll
            for (int ct=0; ct<2; ++ct){
                int col = cwb + ct*16 + n16;
                float bc = bm[col];
#pragma unroll
                for (int rt=0; rt<4; ++rt)
#pragma unroll
                    for (int i=0;i<4;++i){
                        int row = rt*16 + quad*4 + i;
                        int se = seS[row], de = deS[row];
                        float v = silu_(acc[rt][ct][i] + bc
                                        + bf2f(An[(size_t)se*HD+col])
                                        + bf2f(Bn[(size_t)de*HD+col]));
                        T1[row][col] = f2bu(v);
                    }
            }
            __syncthreads();
            {
                int row = tid >> 2, seg = tid & 3;
                if (row0 + row < Ml){
                    const s8v* s = (const s8v*)&T1[row][seg*32];
                    s8v* d = (s8v*)&outM[(size_t)(row0+row)*HD + seg*32];
                    d[0]=s[0]; d[1]=s[1]; d[2]=s[2]; d[3]=s[3];
                }
            }
        } else {
#pragma unroll
            for (int ct=0; ct<2; ++ct){
                int col = cwb + ct*16 + n16;
                float bc = bv1[col];
#pragma unroll
                for (int rt=0; rt<4; ++rt)
#pragma unroll
                    for (int i=0;i<4;++i)
                        T2[rt*16 + quad*4 + i][col] = f2bu(acc[rt][ct][i] + bc);
            }
            __syncthreads();
            {
                int row = tid >> 2, seg = tid & 3;
                if (row0 + row < Ml){
                    const s8v* s = (const s8v*)&T2[row][seg*32];
                    s8v* d = (s8v*)&outG[(size_t)(row0+row)*HD + seg*32];
                    d[0]=s[0]; d[1]=s[1]; d[2]=s[2]; d[3]=s[3];
                }
            }
        }
    }
}

// ---------------- latency phase: per-node edge aggregation ----------------
__global__ __launch_bounds__(128)
void scatter_c(const int* __restrict__ rp, const int* __restrict__ srcp,
               const float* __restrict__ pos,
               const bf16* __restrict__ mB, const bf16* __restrict__ gB,
               const float* __restrict__ xvO,
               float* __restrict__ smC, float* __restrict__ mdC,
               float* __restrict__ avC, float* __restrict__ sdC, int n0, int n1)
{
    const int b = blockIdx.x;
    const int n = n0 + b;
    if (n >= n1) return;
    const int h = threadIdx.x;
    const int cbase = rp[n0];
    int p0 = rp[n], p1 = rp[n+1];
    float px0=pos[n*3],px1=pos[n*3+1],px2=pos[n*3+2];
    float sm=0,a0=0,a1=0,a2=0,m0=0,m1=0,m2=0,d0s=0,d1s=0,d2s=0;
    for (int p=p0;p<p1;++p){
        int ii=p-cbase; if ((unsigned)ii>=(unsigned)ECM) break;
        float mh=bf2f(mB[(size_t)ii*HD+h]);
        float gh=bf2f(gB[(size_t)ii*HD+h]);
        int sn=srcp[p]; sn=min(max(sn,0),NN-1);
        float d0=px0-pos[sn*3], d1=px1-pos[sn*3+1], d2=px2-pos[sn*3+2];
        sm+=mh;
        a0+=xvO[(size_t)sn*3*HD+h]*gh;
        a1+=xvO[(size_t)sn*3*HD+HD+h]*gh;
        a2+=xvO[(size_t)sn*3*HD+2*HD+h]*gh;
        m0+=mh*d0; m1+=mh*d1; m2+=mh*d2;
        d0s+=d0; d1s+=d1; d2s+=d2;
    }
    smC[(size_t)b*HD+h]=sm;
    mdC[(size_t)b*3*HD+h]=m0;
    mdC[(size_t)b*3*HD+HD+h]=m1;
    mdC[(size_t)b*3*HD+2*HD+h]=m2;
    avC[(size_t)b*3*HD+h]=a0;
    avC[(size_t)b*3*HD+HD+h]=a1;
    avC[(size_t)b*3*HD+2*HD+h]=a2;
    if (h==0){ sdC[b*3]=d0s; sdC[b*3+1]=d1s; sdC[b*3+2]=d2s; }
}

// ---------------- compute phase: GEMVs + layernorm/update ----------------
__global__ __launch_bounds__(128)
void nu_fused(const float* __restrict__ smC, const float* __restrict__ mdC,
              const float* __restrict__ avC, const float* __restrict__ sdC,
              const float* __restrict__ xvO, float* __restrict__ xvN,
              float* __restrict__ xs,
              const float* __restrict__ Wv2, const float* __restrict__ bv2,
              const float* __restrict__ Wsx, const float* __restrict__ Wsa,
              const float* __restrict__ bs,
              const float* __restrict__ lng, const float* __restrict__ lnb,
              const float* __restrict__ vsg, int addRes, int n0, int n1)
{
    __shared__ float mdS[NPB][3][128];
    __shared__ float smS[NPB][128];
    __shared__ float xsS[NPB][128];
    __shared__ float red[4];
    __shared__ float red2[2];
    const int h = threadIdx.x;
    const int base = n0 + blockIdx.x*NPB;
    const int cb = blockIdx.x*NPB;
#pragma unroll
    for (int i=0;i<NPB;++i){
        int n = base+i;
        bool valid = n < n1;
        int b = cb+i;
        mdS[i][0][h] = valid ? mdC[(size_t)b*3*HD+h] : 0.f;
        mdS[i][1][h] = valid ? mdC[(size_t)b*3*HD+HD+h] : 0.f;
        mdS[i][2][h] = valid ? mdC[(size_t)b*3*HD+2*HD+h] : 0.f;
        smS[i][h]    = valid ? smC[(size_t)b*HD+h] : 0.f;
        xsS[i][h]    = valid ? xs[(size_t)n*HD+h] : 0.f;
    }
    __syncthreads();
    float g0[NPB],g1v[NPB],g2[NPB],xw[NPB],sw[NPB];
#pragma unroll
    for (int i=0;i<NPB;++i){ g0[i]=0;g1v[i]=0;g2[i]=0;xw[i]=0;sw[i]=0; }
    for (int k=0;k<HD;++k){
        float w2=Wv2[k*HD+h], wx=Wsx[k*HD+h], wa=Wsa[k*HD+h];
#pragma unroll
        for (int i=0;i<NPB;++i){
            g0[i]+=mdS[i][0][k]*w2;
            g1v[i]+=mdS[i][1][k]*w2;
            g2[i]+=mdS[i][2][k]*w2;
            xw[i]+=xsS[i][k]*wx;
            sw[i]+=smS[i][k]*wa;
        }
    }
    const float b2v=bv2[h], bsv=bs[h], lgv=lng[h], lbv=lnb[h], vgv=vsg[h];
    const int w = h >> 6;
    for (int i=0;i<NPB;++i){
        int n = base+i;
        bool valid = n < n1;
        int b = cb+i;
        float xc = xw[i]+sw[i]+bsv;
        float s1=xc, s2=xc*xc;
#pragma unroll
        for (int off=1; off<64; off<<=1){ s1+=__shfl_xor(s1,off,64); s2+=__shfl_xor(s2,off,64); }
        if ((h&63)==0){ red[w*2]=s1; red[w*2+1]=s2; }
        __syncthreads();
        s1=red[0]+red[2]; s2=red[1]+red[3];
        float mu=s1*(1.f/128.f);
        float var=fmaxf(s2*(1.f/128.f)-mu*mu, 0.f);
        float xn=(xc-mu)*rsqrtf(var+1e-5f)*lgv+lbv;
        float ov0=0,ov1=0,ov2=0,a0=0,a1=0,a2=0,d0s=0,d1s=0,d2s=0;
        if (valid){
            ov0=xvO[(size_t)n*3*HD+h];
            ov1=xvO[(size_t)n*3*HD+HD+h];
            ov2=xvO[(size_t)n*3*HD+2*HD+h];
            a0=avC[(size_t)b*3*HD+h];
            a1=avC[(size_t)b*3*HD+HD+h];
            a2=avC[(size_t)b*3*HD+2*HD+h];
            d0s=sdC[b*3]; d1s=sdC[b*3+1]; d2s=sdC[b*3+2];
        }
        float v0=ov0+a0+g0[i]+b2v*d0s;
        float v1=ov1+a1+g1v[i]+b2v*d1s;
        float v2=ov2+a2+g2[i]+b2v*d2s;
        float q=v0*v0+v1*v1+v2*v2;
#pragma unroll
        for (int off=1; off<64; off<<=1) q+=__shfl_xor(q,off,64);
        if ((h&63)==0) red2[w]=q;
        __syncthreads();
        q=fmaxf(red2[0]+red2[1], 0.f);
        float nrm=sqrtf(q*(1.f/128.f)+1e-5f);
        float scale=vgv*sigm_(xn)/nrm;
        float r0=v0*scale, r1=v1*scale, r2=v2*scale;
        float nxs=silu_(xn);
        if (addRes){ nxs+=xsS[i][h]; r0+=ov0; r1+=ov1; r2+=ov2; }
        if (valid){
            xs[(size_t)n*HD+h]=nxs;
            xvN[(size_t)n*3*HD+h]=r0;
            xvN[(size_t)n*3*HD+HD+h]=r1;
            xvN[(size_t)n*3*HD+2*HD+h]=r2;
        }
        __syncthreads();
    }
}

// ---------------- CSR build ----------------
__global__ void hist_kernel(const int* __restrict__ idx, int* __restrict__ cnt, int n, int nb){
    int i = blockIdx.x*256 + threadIdx.x;
    if (i < n){
        int v = idx[i]; v = min(max(v,0), nb-1);
        atomicAdd(&cnt[v], 1);
    }
}

__global__ void scan_kernel(const int* __restrict__ cnt, int* __restrict__ out, int n){
    __shared__ int sums[256];
    int t = threadIdx.x;
    int chunk = (n + 255) / 256;
    int lo = t*chunk, hi = lo+chunk; if (hi > n) hi = n; if (lo > n) lo = n;
    int s = 0;
    for (int i=lo;i<hi;++i) s += cnt[i];
    sums[t] = s;
    __syncthreads();
    if (t==0){ int run=0; for (int i=0;i<256;++i){ int v=sums[i]; sums[i]=run; run+=v; } }
    __syncthreads();
    int run = sums[t];
    for (int i=lo;i<hi;++i){ out[i]=run; run+=cnt[i]; }
    if (hi == n) out[n] = run;
}

__global__ void fill_kernel(const int* __restrict__ src, const int* __restrict__ dst,
                            const int* __restrict__ rowptr, int* __restrict__ cur,
                            int* __restrict__ elist, int* __restrict__ srcp,
                            int* __restrict__ dstp, int n){
    int e = blockIdx.x*256 + threadIdx.x;
    if (e < n){
        int d = dst[e]; d = min(max(d,0), NN-1);
        int slot = atomicAdd(&cur[d], 1);
        int p = rowptr[d] + slot;
        if (p >= 0 && p < NE){
            elist[p] = e;
            int s = src[e];
            srcp[p] = min(max(s,0), NN-1);
            dstp[p] = d;
        }
    }
}

__global__ void gptr_kernel(const int* __restrict__ batch, int* __restrict__ gptr){
    int n = blockIdx.x*256 + threadIdx.x;
    if (n >= NN) return;
    int b = batch[n]; b = min(max(b,0), NB-1);
    if (n == 0){
        for (int g=0; g<=b; ++g) gptr[g] = 0;
    } else {
        int bp = batch[n-1]; bp = min(max(bp,0), NB-1);
        for (int g=bp+1; g<=b; ++g) gptr[g] = n;
    }
    if (n == NN-1){
        for (int g=b+1; g<=NB; ++g) gptr[g] = NN;
    }
}

__global__ void xv_init(const float* __restrict__ xw, const float* __restrict__ pos,
                        float* __restrict__ xv){
    int n = blockIdx.x, h = threadIdx.x;
    float v = xw[(size_t)n*HD+h];
    xv[(size_t)n*3*HD + h]        = v*pos[n*3+0];
    xv[(size_t)n*3*HD + HD + h]   = v*pos[n*3+1];
    xv[(size_t)n*3*HD + 2*HD + h] = v*pos[n*3+2];
}

__global__ __launch_bounds__(128)
void capsule2(const float* __restrict__ Pf, const float* __restrict__ xv,
              const float* __restrict__ pvW, bf16* __restrict__ u){
    __shared__ float Pn[128];
    __shared__ float Xv[3][128];
    __shared__ float dots[48];
    __shared__ float pvn[16];
    __shared__ float capn2[8];
    int n = blockIdx.x, t = threadIdx.x;
    Pn[t] = Pf[(size_t)n*HD + t];
    Xv[0][t] = xv[(size_t)n*3*HD + t];
    Xv[1][t] = xv[(size_t)n*3*HD + HD + t];
    Xv[2][t] = xv[(size_t)n*3*HD + 2*HD + t];
    __syncthreads();
    if (t < 48){
        int pp = t/3, c = t%3;
        float a = 0.f;
        for (int hh=0; hh<128; ++hh) a += Xv[c][hh]*pvW[hh*16+pp];
        dots[t] = a;
    }
    if (t < 8){
        float a = 0.f;
        for (int d=0; d<16; ++d){ float x = Pn[t*16+d]; a += x*x; }
        capn2[t] = a;
    }
    __syncthreads();
    if (t < 16){
        float a = dots[t*3]*dots[t*3] + dots[t*3+1]*dots[t*3+1] + dots[t*3+2]*dots[t*3+2];
        pvn[t] = sqrtf(a + 1e-9f);
    }
    __syncthreads();
    int cap = t >> 4, d = t & 15;
    float n2 = capn2[cap];
    float pcv = Pn[t] * (n2/(1.f+n2)) * rsqrtf(n2 + 1e-9f);
    u[(size_t)n*HD + t] = __float2bfloat16(pcv + pvn[d]);
}

// two-stage pooling: slice WITHIN each graph's node range
__global__ void pool1(const int* __restrict__ gptr, const bf16* __restrict__ u,
                      float* __restrict__ Up){
    int blk = blockIdx.x;            // b*PSL + s
    int b = blk / PSL, s = blk % PSL;
    int h = threadIdx.x;
    int g0 = gptr[b], g1 = gptr[b+1];
    g0 = min(max(g0,0), NN); g1 = min(max(g1,0), NN);
    int len = g1 - g0;
    int lo = g0 + (int)(((long long)len * s) / PSL);
    int hi = g0 + (int)(((long long)len * (s+1)) / PSL);
    float a = 0.f;
    for (int n=lo; n<hi; ++n) a += bf2f(u[(size_t)n*HD + h]);
    Up[(size_t)blk*HD + h] = a;
}

__global__ void pool2(const float* __restrict__ Up, float* __restrict__ U){
    int b = blockIdx.x, h = threadIdx.x;
    float a = 0.f;
    for (int s=0; s<PSL; ++s) a += Up[(size_t)(b*PSL+s)*HD + h];
    U[b*HD + h] = a;
}

__global__ void graph_head(const float* __restrict__ U, const float* __restrict__ sW,
                           const float* __restrict__ aW, const float* __restrict__ ab,
                           const float* __restrict__ pW1, const float* __restrict__ pb1,
                           const float* __restrict__ pg1, const float* __restrict__ pbe1,
                           const float* __restrict__ pW2, const float* __restrict__ pb2,
                           const float* __restrict__ pg2, const float* __restrict__ pbe2,
                           const float* __restrict__ pW3, const float* __restrict__ pb3,
                           float* __restrict__ out){
    __shared__ float Ub[128];
    __shared__ float pooled[2048];
    __shared__ float vv[256];
    __shared__ float bbs[64], ccs[64];
    __shared__ float lg[8], aws[8];
    __shared__ float wcs[32];
    __shared__ float h1[64], h2[32];
    int b = blockIdx.x, t = threadIdx.x;
    if (t < 128) Ub[t] = U[b*HD + t];
    __syncthreads();
#pragma unroll
    for (int j=0;j<8;++j){
        int o = t + 256*j;
        int p = o >> 8, c = (o >> 5) & 7, e = o & 31;
        float a = 0.f;
#pragma unroll
        for (int d=0; d<16; ++d) a += Ub[p*16+d]*sW[((p*16+d)*8+c)*32+e];
        pooled[o] = a;
    }
    __syncthreads();
    {
        float s = 0.f;
        for (int p=0;p<8;++p) s += pooled[p*256 + t];
        s *= 0.125f;
        float n2 = s*s;
#pragma unroll
        for (int off=1; off<32; off<<=1) n2 += __shfl_xor(n2,off,32);
        vv[t] = s*(n2/(1.f+n2))*rsqrtf(n2+1e-9f);
    }
    __syncthreads();
    if (t < 64){
        int p = t>>3, c = t&7;
        float a = 0.f;
        for (int e=0;e<32;++e) a += pooled[p*256+c*32+e]*vv[c*32+e];
        bbs[t] = a;
    }
    __syncthreads();
    if (t < 64){
        int p = t>>3;
        float mx = -1e30f;
        for (int j=0;j<8;++j) mx = fmaxf(mx, bbs[p*8+j]);
        float sum = 0.f;
        for (int j=0;j<8;++j) sum += __expf(bbs[p*8+j]-mx);
        ccs[t] = __expf(bbs[t]-mx)/sum;
    }
    __syncthreads();
    {
        int c = t>>5;
        float s = 0.f;
        for (int p=0;p<8;++p) s += ccs[p*8+c]*pooled[p*256 + t];
        float n2 = s*s;
#pragma unroll
        for (int off=1; off<32; off<<=1) n2 += __shfl_xor(n2,off,32);
        vv[t] = s*(n2/(1.f+n2))*rsqrtf(n2+1e-9f);
    }
    __syncthreads();
    if (t < 8){
        float a = 0.f;
        for (int j=0;j<16;++j) a += vv[t*32+j]*aW[j];
        lg[t] = a + ab[0];
    }
    __syncthreads();
    if (t < 8){
        float mx = -1e30f;
        for (int j=0;j<8;++j) mx = fmaxf(mx, lg[j]);
        float sum = 0.f;
        for (int j=0;j<8;++j) sum += __expf(lg[j]-mx);
        aws[t] = __expf(lg[t]-mx)/sum;
    }
    __syncthreads();
    if (t < 32){
        float a = 0.f;
        for (int c=0;c<8;++c) a += aws[c]*vv[c*32+t];
        wcs[t] = a;
    }
    __syncthreads();
    if (t < 64){
        float a = 0.f;
        for (int e=0;e<32;++e) a += wcs[e]*pW1[e*64+t];
        h1[t] = silu_((a+pb1[t])*pg1[t]+pbe1[t]);
    }
    __syncthreads();
    if (t < 32){
        float a = 0.f;
        for (int j=0;j<64;++j) a += h1[j]*pW2[j*32+t];
        h2[t] = silu_((a+pb2[t])*pg2[t]+pbe2[t]);
    }
    __syncthreads();
    if (t == 0){
        float a = 0.f;
        for (int j=0;j<32;++j) a += h2[j]*pW3[j];
        a += pb3[0];
        if (!finite_(a)) a = 999.f;
        out[b] = a;
    }
}

__global__ void sentinel_k(float* __restrict__ out, float v){
    out[threadIdx.x] = v;
}

// ---------------- host side ----------------
extern "C" void kernel_launch(void* const* d_in, const int* in_sizes, int n_in,
                              void* d_out, int out_size, void* d_ws, size_t ws_size,
                              hipStream_t stream)
{
    (void)in_sizes; (void)n_in; (void)out_size;
    const float* x    = (const float*)d_in[0];
    const float* eat  = (const float*)d_in[1];
    const float* pos  = (const float*)d_in[2];
    const int*  eidx  = (const int*)d_in[3];
    const int*  batch = (const int*)d_in[4];
    const float* neW1=(const float*)d_in[5],  *neb1=(const float*)d_in[6],
               * neg1=(const float*)d_in[7],  *nebe1=(const float*)d_in[8];
    const float* neW2=(const float*)d_in[9],  *neb2=(const float*)d_in[10],
               * neg2=(const float*)d_in[11], *nebe2=(const float*)d_in[12];
    const float* eeW1=(const float*)d_in[13], *eeb1=(const float*)d_in[14];
    const float* eeW2=(const float*)d_in[15], *eeb2=(const float*)d_in[16];
    const float* ivW =(const float*)d_in[17], *ivb =(const float*)d_in[18];
    const float* cWma=(const float*)d_in[19], *cWmb=(const float*)d_in[20],
               * cWme=(const float*)d_in[21], *cbm =(const float*)d_in[22];
    const float* cWsx=(const float*)d_in[23], *cWsa=(const float*)d_in[24],
               * cbs =(const float*)d_in[25];
    const float* cWv1=(const float*)d_in[26], *cbv1=(const float*)d_in[27],
               * cWv2=(const float*)d_in[28], *cbv2=(const float*)d_in[29];
    const float* lng =(const float*)d_in[30], *lnb =(const float*)d_in[31],
               * vsg =(const float*)d_in[32];
    const float* pcW =(const float*)d_in[33], *pcb =(const float*)d_in[34];
    const float* pvW =(const float*)d_in[35];
    const float* sW  =(const float*)d_in[36];
    const float* aW  =(const float*)d_in[37], *ab  =(const float*)d_in[38];
    const float* pW1 =(const float*)d_in[39], *pb1 =(const float*)d_in[40],
               * pg1 =(const float*)d_in[41], *pbe1=(const float*)d_in[42];
    const float* pW2 =(const float*)d_in[43], *pb2 =(const float*)d_in[44],
               * pg2 =(const float*)d_in[45], *pbe2=(const float*)d_in[46];
    const float* pW3 =(const float*)d_in[47], *pb3 =(const float*)d_in[48];

    const int* src = eidx;
    const int* dst = eidx + NE;

    char* wp = (char*)d_ws;
    auto alloc = [&](size_t bytes)->char*{
        char* p = wp;
        wp += (bytes + 255) & ~(size_t)255;
        return p;
    };
    bf16*  bufM  = (bf16*) alloc((size_t)ECM*HD*2);
    bf16*  bufG  = (bf16*) alloc((size_t)ECM*HD*2);
    float* xs    = (float*)alloc((size_t)NN*HD*4);
    float* xvA   = (float*)alloc((size_t)NN*3*HD*4);
    float* xvB   = (float*)alloc((size_t)NN*3*HD*4);
    bf16*  An    = (bf16*) alloc((size_t)NN*HD*2);
    bf16*  Bn    = (bf16*) alloc((size_t)NN*HD*2);
    float* smC   = (float*)alloc((size_t)CN*HD*4);
    float* mdC   = (float*)alloc((size_t)CN*3*HD*4);
    float* avC   = (float*)alloc((size_t)CN*3*HD*4);
    float* sdC   = (float*)alloc((size_t)CN*3*4);
    bf16*  WtH   = (bf16*) alloc((size_t)7*HD*HD*2);
    bf16*  WtL   = (bf16*) alloc((size_t)7*HD*HD*2);
    bf16*  W1h   = (bf16*) alloc((size_t)HD*64*2);
    bf16*  W1l   = (bf16*) alloc((size_t)HD*64*2);
    float* Up    = (float*)alloc((size_t)NB*PSL*HD*4);
    float* Ubuf  = (float*)alloc((size_t)NB*HD*4);
    int* rowptr  = (int*)alloc((size_t)(NN+1)*4);
    int* cnt     = (int*)alloc((size_t)NN*4);
    int* elist   = (int*)alloc((size_t)NE*4);
    int* srcp    = (int*)alloc((size_t)NE*4);
    int* dstp    = (int*)alloc((size_t)NE*4);
    int* gptr    = (int*)alloc((size_t)(NB+1)*4);
    size_t used  = (size_t)(wp - (char*)d_ws);   // ~249 MiB

    if (used > ws_size){
        sentinel_k<<<1, NB, 0, stream>>>((float*)d_out, -1.f - (float)(ws_size >> 20));
        return;
    }
    float* tmpF = xvB;
    bf16*  ubuf = An;
    float* Pf   = xvA;

    // ---- CSR + gptr + weight splits ----
    hipMemsetAsync(cnt, 0, (size_t)NN*4, stream);
    hist_kernel<<<(NE+255)/256, 256, 0, stream>>>(dst, cnt, NE, NN);
    scan_kernel<<<1, 256, 0, stream>>>(cnt, rowptr, NN);
    hipMemsetAsync(cnt, 0, (size_t)NN*4, stream);
    fill_kernel<<<(NE+255)/256, 256, 0, stream>>>(src, dst, rowptr, cnt, elist, srcp, dstp, NE);
    gptr_kernel<<<(NN+255)/256, 256, 0, stream>>>(batch, gptr);
    wprep1<<<32,256,0,stream>>>(eeW1, W1h, W1l);
    wprep<<<64,256,0,stream>>>(eeW2, WtH, WtL);
    for (int l=0;l<3;++l){
        wprep<<<64,256,0,stream>>>(cWme + (size_t)l*HD*HD, WtH + (size_t)(1+l)*HD*HD,
                                   WtL + (size_t)(1+l)*HD*HD);
        wprep<<<64,256,0,stream>>>(cWv1 + (size_t)l*HD*HD, WtH + (size_t)(4+l)*HD*HD,
                                   WtL + (size_t)(4+l)*HD*HD);
    }

    const int GN = (NN+63)/64;
    const int GE = ECM/64;
    const int GS = (CN+NPB-1)/NPB;

    // ---- node embeddings ----
    gemmk<M_BNSILU><<<GN,256,0,stream>>>(x, neW1, neb1, neg1, nebe1, tmpF, 0, NN, 92);
    gemmk<M_BNSILU><<<GN,256,0,stream>>>(tmpF, neW2, neb2, neg2, nebe2, xs, 0, NN, 128);
    gemmk<M_BIAS><<<GN,256,0,stream>>>(xs, ivW, ivb, nullptr, nullptr, tmpF, 0, NN, 128);
    xv_init<<<NN, 128, 0, stream>>>(tmpF, pos, xvA);

    // ---- message-passing layers ----
    float* xvO = xvA;
    float* xvN = xvB;
    for (int l=0; l<3; ++l){
        const float* Wma = cWma + (size_t)l*HD*HD;
        const float* Wmb = cWmb + (size_t)l*HD*HD;
        const float* bm  = cbm  + (size_t)l*HD;
        const float* Wsx = cWsx + (size_t)l*HD*HD;
        const float* Wsa = cWsa + (size_t)l*HD*HD;
        const float* bs  = cbs  + (size_t)l*HD;
        const float* bv1 = cbv1 + (size_t)l*HD;
        const float* Wv2 = cWv2 + (size_t)l*HD*HD;
        const float* bv2 = cbv2 + (size_t)l*HD;
        const bf16* Wmeh = WtH + (size_t)(1+l)*HD*HD;
        const bf16* Wmel = WtL + (size_t)(1+l)*HD*HD;
        const bf16* Wv1h = WtH + (size_t)(4+l)*HD*HD;
        const bf16* Wv1l = WtL + (size_t)(4+l)*HD*HD;

        gemmk<M_PLAIN><<<GN,256,0,stream>>>(xs, Wma, nullptr, nullptr, nullptr, An, 1, NN, 128);
        gemmk<M_PLAIN><<<GN,256,0,stream>>>(xs, Wmb, nullptr, nullptr, nullptr, Bn, 1, NN, 128);

        for (int c=0; c<NCH; ++c){
            int n0 = c*CN, n1 = n0+CN;
            edge_pipe<<<GE,256,0,stream>>>(eat, elist, srcp, dstp,
                                           W1h, W1l, eeb1,
                                           WtH, WtL, eeb2,
                                           Wmeh, Wmel, bm,
                                           An, Bn,
                                           Wv1h, Wv1l, bv1,
                                           rowptr, n0, n1, bufM, bufG);
            scatter_c<<<CN,128,0,stream>>>(rowptr, srcp, pos, bufM, bufG, xvO,
                                           smC, mdC, avC, sdC, n0, n1);
            nu_fused<<<GS,128,0,stream>>>(smC, mdC, avC, sdC,
                                          xvO, xvN, xs,
                                          Wv2, bv2, Wsx, Wsa, bs,
                                          lng + (size_t)l*HD, lnb + (size_t)l*HD,
                                          vsg + (size_t)l*HD, l>0 ? 1 : 0, n0, n1);
        }
        float* t = xvO; xvO = xvN; xvN = t;
    }

    // ---- capsules & head ----
    gemmk<M_BIAS><<<GN,256,0,stream>>>(xs, pcW, pcb, nullptr, nullptr, Pf, 0, NN, 128);
    capsule2<<<NN, 128, 0, stream>>>(Pf, xvO, pvW, ubuf);
    pool1<<<NB*PSL, 128, 0, stream>>>(gptr, ubuf, Up);
    pool2<<<NB, 128, 0, stream>>>(Up, Ubuf);
    graph_head<<<NB, 256, 0, stream>>>(Ubuf, sW, aW, ab,
                                       pW1, pb1, pg1, pbe1,
                                       pW2, pb2, pg2, pbe2,
                                       pW3, pb3, (float*)d_out);
}